// Round 9
// baseline (870.432 us; speedup 1.0000x reference)
//
#include <hip/hip_runtime.h>
#include <math.h>

// Problem constants: D=3, H=64, WIN=8, OUT=32, B=128, T=129
#define BB 128
#define TT 129
#define NSTEP 128
#define NW 16
#define WINW 8
#define OUTD 32
#define NB 2   // batches per block, WAVE-SPECIALIZED: waves 0-3 -> batch A, waves 4-7 -> batch B

typedef _Float16 h2_t __attribute__((ext_vector_type(2)));

__device__ __forceinline__ float fast_rcp(float v){ return __builtin_amdgcn_rcpf(v); }
__device__ __forceinline__ float softplus_f(float v){ return fmaxf(v,0.f)+__logf(1.f+__expf(-fabsf(v))); }
__device__ __forceinline__ float sigmoid_f(float v){ return fast_rcp(1.f+__expf(-v)); }
__device__ __forceinline__ float tanh_f(float v){
    float ax=fminf(fabsf(v),15.f); float e=__expf(2.f*ax);
    float r=1.f-2.f*fast_rcp(e+1.f); return copysignf(r,v);
}
__device__ __forceinline__ float pack2(float a,float b){
    h2_t h; h.x=(_Float16)a; h.y=(_Float16)b; return __builtin_bit_cast(float,h);
}
__device__ __forceinline__ float dot2c(float wc,float ac,float acc){
    return __builtin_amdgcn_fdot2(__builtin_bit_cast(h2_t,wc),__builtin_bit_cast(h2_t,ac),acc,false);
}
__device__ __forceinline__ float dot2q(float4 wq,float4 aq,float acc){
    acc=dot2c(wq.x,aq.x,acc); acc=dot2c(wq.y,aq.y,acc);
    acc=dot2c(wq.z,aq.z,acc); acc=dot2c(wq.w,aq.w,acc); return acc;
}
#define DOT4(acc,Wv,Av) acc += (Wv).x*(Av).x + (Wv).y*(Av).y + (Wv).z*(Av).z + (Wv).w*(Av).w
#define PIN4(v) asm volatile("" : "+v"((v).x), "+v"((v).y), "+v"((v).z), "+v"((v).w))

// DPP cross-lane (VALU-speed). quad_perm domain = 4 consecutive lanes — matches q=t&3 grouping.
#define DPPF(x,ctrl) __builtin_bit_cast(float, __builtin_amdgcn_update_dpp(0, __builtin_bit_cast(int,(x)), (ctrl), 0xF, 0xF, true))
__device__ __forceinline__ float dpp_xor1(float x){ return DPPF(x,0xB1); }   // quad_perm [1,0,3,2]
__device__ __forceinline__ float dpp_xor2(float x){ return DPPF(x,0x4E); }   // quad_perm [2,3,0,1]
__device__ __forceinline__ float dpp_hmir(float x){ return DPPF(x,0x141); }  // row_half_mirror

// Quad-split per batch: lane (r=t>>2, q=t&3) owns rows {r, 64+r, 128+r}, K-slice [q*32, q*32+32).
// Two batches per block on disjoint wave sets -> each SIMD hosts one wave of each batch,
// so one batch's LDS/transcendental stalls are filled by the other batch's VALU issue.
__global__ __launch_bounds__(512, 1)
void ncde_solve(const float* __restrict__ ts, const float* __restrict__ x,
                const float* __restrict__ W0, const float* __restrict__ b0,
                const float* __restrict__ W1, const float* __restrict__ b1,
                const float* __restrict__ W2, const float* __restrict__ b2,
                const float* __restrict__ V0, const float* __restrict__ c0,
                const float* __restrict__ V1, const float* __restrict__ c1,
                const float* __restrict__ V2, const float* __restrict__ c2,
                const float* __restrict__ R, const float* __restrict__ rb,
                float* __restrict__ out)
{
    const int tid = threadIdx.x;
    const int u = tid >> 8;          // batch slot (wave-aligned: waves 0-3 / 4-7)
    const int t = tid & 255;         // per-batch thread id
    const int b = blockIdx.x * NB + u;
    const int r = t >> 2, q = t & 3;
    const int prow = t >> 3, poct = t & 7;

    __shared__ __align__(16) float RSh[OUTD*68];                 // shared read-only
    __shared__ __align__(16) float ySh[NB][64];
    __shared__ __align__(16) float yp[NB][32], y2p[NB][32];      // 64 halves each
    __shared__ __align__(16) float a0H[NB][64], a1H[NB][64];     // 128 halves each
    __shared__ __align__(16) float mpH[NB][96];                  // 192 halves (d-major 3x64)
    __shared__ __align__(16) float u0H[NB][192], u1H[NB][192];   // 384 halves; fp32 scratch in init
    __shared__ float slopesSh[NB][NW][6];
    __shared__ float dtsSh[NB][NSTEP];

    // ---- fp16-packed quad-slice weight carriers: 24 float4 = 96 VGPR (same in both batches) ----
    float4 v0c[2][2], v1c[2][4], v2c[3][4];
    {
        auto pkld = [](const float* src)->float4{
            const float4* p=(const float4*)src;
            float4 a=p[0], c=p[1];
            float4 rr; rr.x=pack2(a.x,a.y); rr.y=pack2(a.z,a.w); rr.z=pack2(c.x,c.y); rr.w=pack2(c.z,c.w);
            return rr;
        };
        #pragma unroll
        for (int i=0;i<2;i++){
            const float* base = V0 + (r+64*i)*64 + q*16;
            v0c[i][0]=pkld(base); v0c[i][1]=pkld(base+8);
        }
        #pragma unroll
        for (int i=0;i<2;i++){
            const float* base = V1 + (r+64*i)*128 + q*32;
            #pragma unroll
            for (int k=0;k<4;k++) v1c[i][k]=pkld(base+8*k);
        }
        #pragma unroll
        for (int i=0;i<3;i++){
            const float* base = V2 + (r+64*i)*128 + q*32;
            #pragma unroll
            for (int k=0;k<4;k++) v2c[i][k]=pkld(base+8*k);
        }
        #pragma unroll
        for (int i=0;i<2;i++){ PIN4(v0c[i][0]); PIN4(v0c[i][1]); }
        #pragma unroll
        for (int i=0;i<2;i++){
            #pragma unroll
            for (int k=0;k<4;k++) PIN4(v1c[i][k]);
        }
        #pragma unroll
        for (int i=0;i<3;i++){
            #pragma unroll
            for (int k=0;k<4;k++) PIN4(v2c[i][k]);
        }
    }
    const float c0A=c0[r], c0B=c0[64+r];
    const float c1A=c1[r], c1B=c1[64+r];
    const float c2A=c2[r], c2B=c2[64+r], c2C=c2[128+r];
    const float rbp = rb[prow];

    for (int i=tid; i<OUTD*64; i+=512) RSh[(i>>6)*68 + (i&63)] = R[i];
    const float* tsb = ts + (size_t)b*TT;
    for (int i=t; i<NSTEP; i+=256) dtsSh[u][i] = tsb[i+1] - tsb[i];

    // ---- log-signature slopes (per batch, threads 0..15) ----
    if (t < NW) {
        const int w = t;
        const float* xs = x + (size_t)(b*TT + w*WINW)*3;
        float x0c[3] = {xs[0], xs[1], xs[2]};
        float prev[3] = {x0c[0], x0c[1], x0c[2]};
        float am01=0.f, am02=0.f, am12=0.f, am10=0.f, am20=0.f, am21=0.f;
        #pragma unroll
        for (int k=0;k<WINW;k++) {
            float cur[3] = {xs[(k+1)*3+0], xs[(k+1)*3+1], xs[(k+1)*3+2]};
            float rel[3], dv[3];
            #pragma unroll
            for (int c=0;c<3;c++){ rel[c]=prev[c]-x0c[c]; dv[c]=cur[c]-prev[c]; }
            am01 += rel[0]*dv[1]; am10 += rel[1]*dv[0];
            am02 += rel[0]*dv[2]; am20 += rel[2]*dv[0];
            am12 += rel[1]*dv[2]; am21 += rel[2]*dv[1];
            prev[0]=cur[0]; prev[1]=cur[1]; prev[2]=cur[2];
        }
        const float invden = 1.f/(tsb[(w+1)*WINW] - tsb[w*WINW]);
        slopesSh[u][w][0] = (prev[0]-x0c[0])*invden;
        slopesSh[u][w][1] = (prev[1]-x0c[1])*invden;
        slopesSh[u][w][2] = (prev[2]-x0c[2])*invden;
        slopesSh[u][w][3] = 0.5f*(am01-am10)*invden;
        slopesSh[u][w][4] = 0.5f*(am02-am20)*invden;
        slopesSh[u][w][5] = 0.5f*(am12-am21)*invden;
    }

    // ---- h0 = init_mlp(x[b,0,:]) fp32 (u0H/u1H as scratch, per batch) ----
    if (t < 128) {
        const float xv0 = x[(size_t)b*TT*3+0];
        const float xv1 = x[(size_t)b*TT*3+1];
        const float xv2 = x[(size_t)b*TT*3+2];
        float acc = b0[t] + W0[t*3]*xv0 + W0[t*3+1]*xv1 + W0[t*3+2]*xv2;
        u0H[u][t] = softplus_f(acc);
    }
    __syncthreads();
    if (t < 128) {
        float acc = b1[t];
        const float4* rw = (const float4*)(W1 + t*128);
        #pragma unroll 8
        for (int k=0;k<32;k++){ float4 wv=rw[k]; float4 av=*(const float4*)&u0H[u][4*k]; DOT4(acc,wv,av); }
        u1H[u][t] = softplus_f(acc);
    }
    __syncthreads();
    if (t < 64) {
        float acc = b2[t];
        const float4* rw = (const float4*)(W2 + t*128);
        #pragma unroll 8
        for (int k=0;k<32;k++){ float4 wv=rw[k]; float4 av=*(const float4*)&u1H[u][4*k]; DOT4(acc,wv,av); }
        ySh[u][t] = acc;
        ((_Float16*)yp[u])[t] = (_Float16)acc;
    }
    __syncthreads();

    float yreg = ySh[u][r];   // lane-local state (quad-redundant)
    float k1r = 0.f;
    float S0,S1,S2,S3,S4,S5;

    auto Feval = [&](const float* ypIn, bool first, float dtc) {
        float sig0A,sig0B,sig1A,sig1B,mA,mB,mC,dtA,dtB,dtC;
        // S1: z0 = V0@y + c0  (rows r, 64+r; K-slice q)
        {
            const float4* Y = (const float4*)ypIn + q*2;
            float4 y0=Y[0], y1=Y[1];
            float zA=0.f, zB=0.f;
            zA=dot2q(v0c[0][0],y0,zA); zA=dot2q(v0c[0][1],y1,zA);
            zB=dot2q(v0c[1][0],y0,zB); zB=dot2q(v0c[1][1],y1,zB);
            zA += dpp_xor1(zA); zA += dpp_xor2(zA); zA += c0A;
            zB += dpp_xor1(zB); zB += dpp_xor2(zB); zB += c0B;
            sig0A=sigmoid_f(zA); sig0B=sigmoid_f(zB);
            if (!q){
                ((_Float16*)a0H[u])[r]    = (_Float16)softplus_f(zA);
                ((_Float16*)a0H[u])[64+r] = (_Float16)softplus_f(zB);
            }
        }
        __syncthreads();
        // S2: z1 = V1@a0 + c1
        {
            const float4* A = (const float4*)a0H[u] + q*4;
            float4 a0=A[0],a1=A[1],a2=A[2],a3=A[3];
            float zA=0.f, zB=0.f;
            zA=dot2q(v1c[0][0],a0,zA); zA=dot2q(v1c[0][1],a1,zA); zA=dot2q(v1c[0][2],a2,zA); zA=dot2q(v1c[0][3],a3,zA);
            zB=dot2q(v1c[1][0],a0,zB); zB=dot2q(v1c[1][1],a1,zB); zB=dot2q(v1c[1][2],a2,zB); zB=dot2q(v1c[1][3],a3,zB);
            zA += dpp_xor1(zA); zA += dpp_xor2(zA); zA += c1A;
            zB += dpp_xor1(zB); zB += dpp_xor2(zB); zB += c1B;
            sig1A=sigmoid_f(zA); sig1B=sigmoid_f(zB);
            if (!q){
                ((_Float16*)a1H[u])[r]    = (_Float16)softplus_f(zA);
                ((_Float16*)a1H[u])[64+r] = (_Float16)softplus_f(zB);
            }
        }
        __syncthreads();
        // S3: m = tanh(V2@a1 + c2)  (rows r, 64+r, 128+r)
        {
            const float4* A = (const float4*)a1H[u] + q*4;
            float4 a0=A[0],a1=A[1],a2=A[2],a3=A[3];
            float zA=0.f, zB=0.f, zC=0.f;
            zA=dot2q(v2c[0][0],a0,zA); zA=dot2q(v2c[0][1],a1,zA); zA=dot2q(v2c[0][2],a2,zA); zA=dot2q(v2c[0][3],a3,zA);
            zB=dot2q(v2c[1][0],a0,zB); zB=dot2q(v2c[1][1],a1,zB); zB=dot2q(v2c[1][2],a2,zB); zB=dot2q(v2c[1][3],a3,zB);
            zC=dot2q(v2c[2][0],a0,zC); zC=dot2q(v2c[2][1],a1,zC); zC=dot2q(v2c[2][2],a2,zC); zC=dot2q(v2c[2][3],a3,zC);
            zA += dpp_xor1(zA); zA += dpp_xor2(zA);
            zB += dpp_xor1(zB); zB += dpp_xor2(zB);
            zC += dpp_xor1(zC); zC += dpp_xor2(zC);
            mA=tanh_f(zA+c2A); mB=tanh_f(zB+c2B); mC=tanh_f(zC+c2C);
            dtA=1.f-mA*mA; dtB=1.f-mB*mB; dtC=1.f-mC*mC;
            if (!q){
                ((_Float16*)mpH[u])[r]     = (_Float16)mA;
                ((_Float16*)mpH[u])[64+r]  = (_Float16)mB;
                ((_Float16*)mpH[u])[128+r] = (_Float16)mC;
            }
        }
        __syncthreads();
        // S4: u0[d] = sig0 ⊙ (V0 @ m[d])
        {
            const float4* M = (const float4*)mpH[u];
            float4 g00=M[q*2], g01=M[q*2+1];
            float4 g10=M[8+q*2], g11=M[8+q*2+1];
            float4 g20=M[16+q*2], g21=M[16+q*2+1];
            float t0A=0.f,t1A=0.f,t2A=0.f,t0B=0.f,t1B=0.f,t2B=0.f;
            t0A=dot2q(v0c[0][0],g00,t0A); t0A=dot2q(v0c[0][1],g01,t0A);
            t1A=dot2q(v0c[0][0],g10,t1A); t1A=dot2q(v0c[0][1],g11,t1A);
            t2A=dot2q(v0c[0][0],g20,t2A); t2A=dot2q(v0c[0][1],g21,t2A);
            t0B=dot2q(v0c[1][0],g00,t0B); t0B=dot2q(v0c[1][1],g01,t0B);
            t1B=dot2q(v0c[1][0],g10,t1B); t1B=dot2q(v0c[1][1],g11,t1B);
            t2B=dot2q(v0c[1][0],g20,t2B); t2B=dot2q(v0c[1][1],g21,t2B);
            t0A += dpp_xor1(t0A); t0A += dpp_xor2(t0A);
            t1A += dpp_xor1(t1A); t1A += dpp_xor2(t1A);
            t2A += dpp_xor1(t2A); t2A += dpp_xor2(t2A);
            t0B += dpp_xor1(t0B); t0B += dpp_xor2(t0B);
            t1B += dpp_xor1(t1B); t1B += dpp_xor2(t1B);
            t2B += dpp_xor1(t2B); t2B += dpp_xor2(t2B);
            if (!q){
                ((_Float16*)u0H[u])[r]      = (_Float16)(sig0A*t0A);
                ((_Float16*)u0H[u])[64+r]   = (_Float16)(sig0B*t0B);
                ((_Float16*)u0H[u])[128+r]  = (_Float16)(sig0A*t1A);
                ((_Float16*)u0H[u])[192+r]  = (_Float16)(sig0B*t1B);
                ((_Float16*)u0H[u])[256+r]  = (_Float16)(sig0A*t2A);
                ((_Float16*)u0H[u])[320+r]  = (_Float16)(sig0B*t2B);
            }
        }
        __syncthreads();
        // S5: u1[d] = sig1 ⊙ (V1 @ u0[d])
        {
            const float4* U = (const float4*)u0H[u];
            float4 g0[4],g1[4],g2[4];
            #pragma unroll
            for (int k=0;k<4;k++){ g0[k]=U[q*4+k]; g1[k]=U[16+q*4+k]; g2[k]=U[32+q*4+k]; }
            float t0A=0.f,t1A=0.f,t2A=0.f,t0B=0.f,t1B=0.f,t2B=0.f;
            #pragma unroll
            for (int k=0;k<4;k++){
                float4 wa=v1c[0][k], wb=v1c[1][k];
                t0A=dot2q(wa,g0[k],t0A); t1A=dot2q(wa,g1[k],t1A); t2A=dot2q(wa,g2[k],t2A);
                t0B=dot2q(wb,g0[k],t0B); t1B=dot2q(wb,g1[k],t1B); t2B=dot2q(wb,g2[k],t2B);
            }
            t0A += dpp_xor1(t0A); t0A += dpp_xor2(t0A);
            t1A += dpp_xor1(t1A); t1A += dpp_xor2(t1A);
            t2A += dpp_xor1(t2A); t2A += dpp_xor2(t2A);
            t0B += dpp_xor1(t0B); t0B += dpp_xor2(t0B);
            t1B += dpp_xor1(t1B); t1B += dpp_xor2(t1B);
            t2B += dpp_xor1(t2B); t2B += dpp_xor2(t2B);
            if (!q){
                ((_Float16*)u1H[u])[r]      = (_Float16)(sig1A*t0A);
                ((_Float16*)u1H[u])[64+r]   = (_Float16)(sig1B*t0B);
                ((_Float16*)u1H[u])[128+r]  = (_Float16)(sig1A*t1A);
                ((_Float16*)u1H[u])[192+r]  = (_Float16)(sig1B*t1B);
                ((_Float16*)u1H[u])[256+r]  = (_Float16)(sig1A*t2A);
                ((_Float16*)u1H[u])[320+r]  = (_Float16)(sig1B*t2B);
            }
        }
        __syncthreads();
        // S6+S7 fused: J rows {r,64+r,128+r} x skip-diagonal tangents all lane-local.
        {
            const float4* U = (const float4*)u1H[u];
            float4 g0[4],g1[4],g2[4];
            #pragma unroll
            for (int k=0;k<4;k++){ g0[k]=U[q*4+k]; g1[k]=U[16+q*4+k]; g2[k]=U[32+q*4+k]; }
            float J1r=0.f,J2r=0.f,J0m=0.f,J2m=0.f,J0t=0.f,J1t=0.f;
            #pragma unroll
            for (int k=0;k<4;k++){
                float4 wa=v2c[0][k], wb=v2c[1][k], wc=v2c[2][k];
                J1r=dot2q(wa,g1[k],J1r); J2r=dot2q(wa,g2[k],J2r);
                J0m=dot2q(wb,g0[k],J0m); J2m=dot2q(wb,g2[k],J2m);
                J0t=dot2q(wc,g0[k],J0t); J1t=dot2q(wc,g1[k],J1t);
            }
            J1r += dpp_xor1(J1r); J1r += dpp_xor2(J1r);
            J2r += dpp_xor1(J2r); J2r += dpp_xor2(J2r);
            J0m += dpp_xor1(J0m); J0m += dpp_xor2(J0m);
            J2m += dpp_xor1(J2m); J2m += dpp_xor2(J2m);
            J0t += dpp_xor1(J0t); J0t += dpp_xor2(J0t);
            J1t += dpp_xor1(J1t); J1t += dpp_xor2(J1t);
            J1r*=dtA; J2r*=dtA; J0m*=dtB; J2m*=dtB; J0t*=dtC; J1t*=dtC;
            float kk = mA*S0 + mB*S1 + mC*S2
                     + S3*(J0m - J1r) + S4*(J0t - J2r) + S5*(J1t - J2m);
            if (first){
                k1r = kk;
                float y2 = yreg + dtc*kk;
                if (!q) ((_Float16*)y2p[u])[r] = (_Float16)y2;
            } else {
                yreg += 0.5f*dtc*(k1r + kk);
                if (!q){ ((_Float16*)yp[u])[r] = (_Float16)yreg; ySh[u][r] = yreg; }
            }
        }
        __syncthreads();
    };

    // ---- projection (fp32, overlapped with S1's interval) ----
    auto proj = [&](int stp) {
        const float4* rr = (const float4*)(RSh + prow*68 + poct*8);
        const float4* yy = (const float4*)(ySh[u] + poct*8);
        float pacc = 0.f;
        DOT4(pacc, rr[0], yy[0]); DOT4(pacc, rr[1], yy[1]);
        pacc += dpp_xor1(pacc);
        pacc += dpp_xor2(pacc);
        pacc += dpp_hmir(pacc);
        if (!poct) out[(size_t)(b*TT + stp)*OUTD + prow] = tanh_f(pacc + rbp);
    };

    // ---- Heun scan (both batches in lockstep on disjoint waves) ----
    for (int step=0; step<NSTEP; ++step) {
        proj(step);
        const int w = step >> 3;
        S0=slopesSh[u][w][0]; S1=slopesSh[u][w][1]; S2=slopesSh[u][w][2];
        S3=slopesSh[u][w][3]; S4=slopesSh[u][w][4]; S5=slopesSh[u][w][5];
        const float dtc = dtsSh[u][step];
        Feval(yp[u],  true,  dtc);
        Feval(y2p[u], false, dtc);
    }
    proj(NSTEP);
}

extern "C" void kernel_launch(void* const* d_in, const int* in_sizes, int n_in,
                              void* d_out, int out_size, void* d_ws, size_t ws_size,
                              hipStream_t stream) {
    const float* ts = (const float*)d_in[0];
    const float* x  = (const float*)d_in[1];
    const float* W0 = (const float*)d_in[2];
    const float* b0 = (const float*)d_in[3];
    const float* W1 = (const float*)d_in[4];
    const float* b1 = (const float*)d_in[5];
    const float* W2 = (const float*)d_in[6];
    const float* b2 = (const float*)d_in[7];
    const float* V0 = (const float*)d_in[8];
    const float* c0 = (const float*)d_in[9];
    const float* V1 = (const float*)d_in[10];
    const float* c1 = (const float*)d_in[11];
    const float* V2 = (const float*)d_in[12];
    const float* c2 = (const float*)d_in[13];
    const float* R  = (const float*)d_in[14];
    const float* rb = (const float*)d_in[15];
    float* out = (float*)d_out;

    ncde_solve<<<dim3(BB/NB), dim3(512), 0, stream>>>(
        ts, x, W0, b0, W1, b1, W2, b2, V0, c0, V1, c1, V2, c2, R, rb, out);
}

// Round 10
// 691.990 us; speedup vs baseline: 1.2579x; 1.2579x over previous
//
#include <hip/hip_runtime.h>
#include <math.h>

// Problem constants: D=3, H=64, WIN=8, OUT=32, B=128, T=129
#define BB 128
#define TT 129
#define NSTEP 128
#define NW 16
#define WINW 8
#define OUTD 32

typedef _Float16 h2_t __attribute__((ext_vector_type(2)));

__device__ __forceinline__ float fast_rcp(float v){ return __builtin_amdgcn_rcpf(v); }
__device__ __forceinline__ float softplus_f(float v){ return fmaxf(v,0.f)+__logf(1.f+__expf(-fabsf(v))); }
__device__ __forceinline__ float sigmoid_f(float v){ return fast_rcp(1.f+__expf(-v)); }
__device__ __forceinline__ float tanh_f(float v){
    float ax=fminf(fabsf(v),15.f); float e=__expf(2.f*ax);
    float r=1.f-2.f*fast_rcp(e+1.f); return copysignf(r,v);
}
__device__ __forceinline__ float pack2(float a,float b){
    h2_t h; h.x=(_Float16)a; h.y=(_Float16)b; return __builtin_bit_cast(float,h);
}
__device__ __forceinline__ float dot2c(float wc,float ac,float acc){
    return __builtin_amdgcn_fdot2(__builtin_bit_cast(h2_t,wc),__builtin_bit_cast(h2_t,ac),acc,false);
}
__device__ __forceinline__ float dot2q(float4 wq,float4 aq,float acc){
    acc=dot2c(wq.x,aq.x,acc); acc=dot2c(wq.y,aq.y,acc);
    acc=dot2c(wq.z,aq.z,acc); acc=dot2c(wq.w,aq.w,acc); return acc;
}
#define DOT4(acc,Wv,Av) acc += (Wv).x*(Av).x + (Wv).y*(Av).y + (Wv).z*(Av).z + (Wv).w*(Av).w
#define PIN4(v) asm volatile("" : "+v"((v).x), "+v"((v).y), "+v"((v).z), "+v"((v).w))

// DPP cross-lane (VALU-speed).
#define DPPF(x,ctrl) __builtin_bit_cast(float, __builtin_amdgcn_update_dpp(0, __builtin_bit_cast(int,(x)), (ctrl), 0xF, 0xF, true))
__device__ __forceinline__ float dpp_xor1(float x){ return DPPF(x,0xB1); }   // quad_perm [1,0,3,2]
__device__ __forceinline__ float dpp_xor2(float x){ return DPPF(x,0x4E); }   // quad_perm [2,3,0,1]
__device__ __forceinline__ float dpp_hmir(float x){ return DPPF(x,0x141); }  // row_half_mirror: i <- (i&~7)+(7-(i&7))
// full 8-lane-group sum, valid in every lane of the group
#define RED8(x) do{ x += dpp_xor1(x); x += dpp_xor2(x); x += dpp_hmir(x); }while(0)

// Octal-split, 1 batch per block, 512 threads (8 waves -> 2 waves/SIMD on 128 CUs):
// lane (r=t>>3, q=t&7) owns rows {r, 64+r, 128+r}, K-slice [q*16, q*16+16) halves.
// Two waves per SIMD of the SAME batch: one wave's LDS/transcendental stall is filled
// by the co-resident wave's VALU issue (mechanism measured in round 9: 630cy/stage).
__global__ __launch_bounds__(512, 1)
void ncde_solve(const float* __restrict__ ts, const float* __restrict__ x,
                const float* __restrict__ W0, const float* __restrict__ b0,
                const float* __restrict__ W1, const float* __restrict__ b1,
                const float* __restrict__ W2, const float* __restrict__ b2,
                const float* __restrict__ V0, const float* __restrict__ c0,
                const float* __restrict__ V1, const float* __restrict__ c1,
                const float* __restrict__ V2, const float* __restrict__ c2,
                const float* __restrict__ R, const float* __restrict__ rb,
                float* __restrict__ out)
{
    const int b = blockIdx.x;
    const int t = threadIdx.x;          // 0..511
    const int r = t >> 3, q = t & 7;    // row slot, K-slice
    const int prow = t >> 3, poct = t & 7;  // projection (threads 0..255 only)

    __shared__ __align__(16) float RSh[OUTD*68];
    __shared__ __align__(16) float ySh[64];
    __shared__ __align__(16) float yp[32], y2p[32];      // 64 halves each
    __shared__ __align__(16) float a0H[64], a1H[64];     // 128 halves each
    __shared__ __align__(16) float mpH[96];              // 192 halves (d-major 3x64)
    __shared__ __align__(16) float u0H[192], u1H[192];   // 384 halves (d-major 3x128); fp32 scratch in init
    __shared__ float slopesSh[NW][6];
    __shared__ float dtsSh[NSTEP];

    // ---- fp16-packed octal-slice weight carriers: 12 float4 = 48 VGPR ----
    float4 v0c[2], v1c[2][2], v2c[3][2];
    {
        auto pkld = [](const float* src)->float4{
            const float4* p=(const float4*)src;
            float4 a=p[0], c=p[1];
            float4 rr; rr.x=pack2(a.x,a.y); rr.y=pack2(a.z,a.w); rr.z=pack2(c.x,c.y); rr.w=pack2(c.z,c.w);
            return rr;
        };
        #pragma unroll
        for (int i=0;i<2;i++) v0c[i]=pkld(V0 + (r+64*i)*64 + q*8);
        #pragma unroll
        for (int i=0;i<2;i++){
            const float* base = V1 + (r+64*i)*128 + q*16;
            v1c[i][0]=pkld(base); v1c[i][1]=pkld(base+8);
        }
        #pragma unroll
        for (int i=0;i<3;i++){
            const float* base = V2 + (r+64*i)*128 + q*16;
            v2c[i][0]=pkld(base); v2c[i][1]=pkld(base+8);
        }
        #pragma unroll
        for (int i=0;i<2;i++) PIN4(v0c[i]);
        #pragma unroll
        for (int i=0;i<2;i++){ PIN4(v1c[i][0]); PIN4(v1c[i][1]); }
        #pragma unroll
        for (int i=0;i<3;i++){ PIN4(v2c[i][0]); PIN4(v2c[i][1]); }
    }
    const float c0A=c0[r], c0B=c0[64+r];
    const float c1A=c1[r], c1B=c1[64+r];
    const float c2A=c2[r], c2B=c2[64+r], c2C=c2[128+r];
    const float rbp = rb[prow & 31];

    for (int i=t; i<OUTD*64; i+=512) RSh[(i>>6)*68 + (i&63)] = R[i];
    const float* tsb = ts + (size_t)b*TT;
    if (t < NSTEP) dtsSh[t] = tsb[t+1] - tsb[t];

    // ---- log-signature slopes (threads 0..15) ----
    if (t < NW) {
        const int w = t;
        const float* xs = x + (size_t)(b*TT + w*WINW)*3;
        float x0c[3] = {xs[0], xs[1], xs[2]};
        float prev[3] = {x0c[0], x0c[1], x0c[2]};
        float am01=0.f, am02=0.f, am12=0.f, am10=0.f, am20=0.f, am21=0.f;
        #pragma unroll
        for (int k=0;k<WINW;k++) {
            float cur[3] = {xs[(k+1)*3+0], xs[(k+1)*3+1], xs[(k+1)*3+2]};
            float rel[3], dv[3];
            #pragma unroll
            for (int c=0;c<3;c++){ rel[c]=prev[c]-x0c[c]; dv[c]=cur[c]-prev[c]; }
            am01 += rel[0]*dv[1]; am10 += rel[1]*dv[0];
            am02 += rel[0]*dv[2]; am20 += rel[2]*dv[0];
            am12 += rel[1]*dv[2]; am21 += rel[2]*dv[1];
            prev[0]=cur[0]; prev[1]=cur[1]; prev[2]=cur[2];
        }
        const float invden = 1.f/(tsb[(w+1)*WINW] - tsb[w*WINW]);
        slopesSh[w][0] = (prev[0]-x0c[0])*invden;
        slopesSh[w][1] = (prev[1]-x0c[1])*invden;
        slopesSh[w][2] = (prev[2]-x0c[2])*invden;
        slopesSh[w][3] = 0.5f*(am01-am10)*invden;
        slopesSh[w][4] = 0.5f*(am02-am20)*invden;
        slopesSh[w][5] = 0.5f*(am12-am21)*invden;
    }

    // ---- h0 = init_mlp(x[b,0,:]) fp32 (u0H/u1H as scratch) ----
    if (t < 128) {
        const float xv0 = x[(size_t)b*TT*3+0];
        const float xv1 = x[(size_t)b*TT*3+1];
        const float xv2 = x[(size_t)b*TT*3+2];
        float acc = b0[t] + W0[t*3]*xv0 + W0[t*3+1]*xv1 + W0[t*3+2]*xv2;
        u0H[t] = softplus_f(acc);
    }
    __syncthreads();
    if (t < 128) {
        float acc = b1[t];
        const float4* rw = (const float4*)(W1 + t*128);
        #pragma unroll 8
        for (int k=0;k<32;k++){ float4 wv=rw[k]; float4 av=*(const float4*)&u0H[4*k]; DOT4(acc,wv,av); }
        u1H[t] = softplus_f(acc);
    }
    __syncthreads();
    if (t < 64) {
        float acc = b2[t];
        const float4* rw = (const float4*)(W2 + t*128);
        #pragma unroll 8
        for (int k=0;k<32;k++){ float4 wv=rw[k]; float4 av=*(const float4*)&u1H[4*k]; DOT4(acc,wv,av); }
        ySh[t] = acc;
        ((_Float16*)yp)[t] = (_Float16)acc;
    }
    __syncthreads();

    float yreg = ySh[r];    // lane-local state (8x redundant per row)
    float k1r = 0.f;
    float S0,S1,S2,S3,S4,S5;

    auto Feval = [&](const float* ypIn, bool first, float dtc) {
        float sig0A,sig0B,sig1A,sig1B,mA,mB,mC,dtA,dtB,dtC;
        // S1: z0 = V0@y + c0  (rows r, 64+r; K-slice q: 1 f4)
        {
            float4 y0 = ((const float4*)ypIn)[q];
            float zA=dot2q(v0c[0],y0,0.f);
            float zB=dot2q(v0c[1],y0,0.f);
            RED8(zA); RED8(zB);
            zA += c0A; zB += c0B;
            sig0A=sigmoid_f(zA); sig0B=sigmoid_f(zB);
            if (!q){
                ((_Float16*)a0H)[r]    = (_Float16)softplus_f(zA);
                ((_Float16*)a0H)[64+r] = (_Float16)softplus_f(zB);
            }
        }
        __syncthreads();
        // S2: z1 = V1@a0 + c1  (2 f4 slice)
        {
            const float4* A = (const float4*)a0H + q*2;
            float4 a0=A[0], a1=A[1];
            float zA=dot2q(v1c[0][0],a0,0.f); zA=dot2q(v1c[0][1],a1,zA);
            float zB=dot2q(v1c[1][0],a0,0.f); zB=dot2q(v1c[1][1],a1,zB);
            RED8(zA); RED8(zB);
            zA += c1A; zB += c1B;
            sig1A=sigmoid_f(zA); sig1B=sigmoid_f(zB);
            if (!q){
                ((_Float16*)a1H)[r]    = (_Float16)softplus_f(zA);
                ((_Float16*)a1H)[64+r] = (_Float16)softplus_f(zB);
            }
        }
        __syncthreads();
        // S3: m = tanh(V2@a1 + c2)  (rows r, 64+r, 128+r)
        {
            const float4* A = (const float4*)a1H + q*2;
            float4 a0=A[0], a1=A[1];
            float zA=dot2q(v2c[0][0],a0,0.f); zA=dot2q(v2c[0][1],a1,zA);
            float zB=dot2q(v2c[1][0],a0,0.f); zB=dot2q(v2c[1][1],a1,zB);
            float zC=dot2q(v2c[2][0],a0,0.f); zC=dot2q(v2c[2][1],a1,zC);
            RED8(zA); RED8(zB); RED8(zC);
            mA=tanh_f(zA+c2A); mB=tanh_f(zB+c2B); mC=tanh_f(zC+c2C);
            dtA=1.f-mA*mA; dtB=1.f-mB*mB; dtC=1.f-mC*mC;
            if (!q){
                ((_Float16*)mpH)[r]     = (_Float16)mA;
                ((_Float16*)mpH)[64+r]  = (_Float16)mB;
                ((_Float16*)mpH)[128+r] = (_Float16)mC;
            }
        }
        __syncthreads();
        // S4: u0[d] = sig0 ⊙ (V0 @ m[d])  (1 f4 per d)
        {
            const float4* M = (const float4*)mpH;
            float4 g0=M[q], g1=M[8+q], g2=M[16+q];
            float t0A=dot2q(v0c[0],g0,0.f), t1A=dot2q(v0c[0],g1,0.f), t2A=dot2q(v0c[0],g2,0.f);
            float t0B=dot2q(v0c[1],g0,0.f), t1B=dot2q(v0c[1],g1,0.f), t2B=dot2q(v0c[1],g2,0.f);
            RED8(t0A); RED8(t1A); RED8(t2A);
            RED8(t0B); RED8(t1B); RED8(t2B);
            if (!q){
                ((_Float16*)u0H)[r]      = (_Float16)(sig0A*t0A);
                ((_Float16*)u0H)[64+r]   = (_Float16)(sig0B*t0B);
                ((_Float16*)u0H)[128+r]  = (_Float16)(sig0A*t1A);
                ((_Float16*)u0H)[192+r]  = (_Float16)(sig0B*t1B);
                ((_Float16*)u0H)[256+r]  = (_Float16)(sig0A*t2A);
                ((_Float16*)u0H)[320+r]  = (_Float16)(sig0B*t2B);
            }
        }
        __syncthreads();
        // S5: u1[d] = sig1 ⊙ (V1 @ u0[d])  (2 f4 per d)
        {
            const float4* U = (const float4*)u0H;
            float4 g0a=U[q*2],    g0b=U[q*2+1];
            float4 g1a=U[16+q*2], g1b=U[16+q*2+1];
            float4 g2a=U[32+q*2], g2b=U[32+q*2+1];
            float t0A=dot2q(v1c[0][0],g0a,0.f); t0A=dot2q(v1c[0][1],g0b,t0A);
            float t1A=dot2q(v1c[0][0],g1a,0.f); t1A=dot2q(v1c[0][1],g1b,t1A);
            float t2A=dot2q(v1c[0][0],g2a,0.f); t2A=dot2q(v1c[0][1],g2b,t2A);
            float t0B=dot2q(v1c[1][0],g0a,0.f); t0B=dot2q(v1c[1][1],g0b,t0B);
            float t1B=dot2q(v1c[1][0],g1a,0.f); t1B=dot2q(v1c[1][1],g1b,t1B);
            float t2B=dot2q(v1c[1][0],g2a,0.f); t2B=dot2q(v1c[1][1],g2b,t2B);
            RED8(t0A); RED8(t1A); RED8(t2A);
            RED8(t0B); RED8(t1B); RED8(t2B);
            if (!q){
                ((_Float16*)u1H)[r]      = (_Float16)(sig1A*t0A);
                ((_Float16*)u1H)[64+r]   = (_Float16)(sig1B*t0B);
                ((_Float16*)u1H)[128+r]  = (_Float16)(sig1A*t1A);
                ((_Float16*)u1H)[192+r]  = (_Float16)(sig1B*t1B);
                ((_Float16*)u1H)[256+r]  = (_Float16)(sig1A*t2A);
                ((_Float16*)u1H)[320+r]  = (_Float16)(sig1B*t2B);
            }
        }
        __syncthreads();
        // S6+S7 fused: J rows {r,64+r,128+r} x skip-diagonal tangents all lane-local.
        {
            const float4* U = (const float4*)u1H;
            float4 g0a=U[q*2],    g0b=U[q*2+1];
            float4 g1a=U[16+q*2], g1b=U[16+q*2+1];
            float4 g2a=U[32+q*2], g2b=U[32+q*2+1];
            float J1r=dot2q(v2c[0][0],g1a,0.f); J1r=dot2q(v2c[0][1],g1b,J1r);
            float J2r=dot2q(v2c[0][0],g2a,0.f); J2r=dot2q(v2c[0][1],g2b,J2r);
            float J0m=dot2q(v2c[1][0],g0a,0.f); J0m=dot2q(v2c[1][1],g0b,J0m);
            float J2m=dot2q(v2c[1][0],g2a,0.f); J2m=dot2q(v2c[1][1],g2b,J2m);
            float J0t=dot2q(v2c[2][0],g0a,0.f); J0t=dot2q(v2c[2][1],g0b,J0t);
            float J1t=dot2q(v2c[2][0],g1a,0.f); J1t=dot2q(v2c[2][1],g1b,J1t);
            RED8(J1r); RED8(J2r); RED8(J0m); RED8(J2m); RED8(J0t); RED8(J1t);
            J1r*=dtA; J2r*=dtA; J0m*=dtB; J2m*=dtB; J0t*=dtC; J1t*=dtC;
            float kk = mA*S0 + mB*S1 + mC*S2
                     + S3*(J0m - J1r) + S4*(J0t - J2r) + S5*(J1t - J2m);
            if (first){
                k1r = kk;
                float y2 = yreg + dtc*kk;
                if (!q) ((_Float16*)y2p)[r] = (_Float16)y2;
            } else {
                yreg += 0.5f*dtc*(k1r + kk);
                if (!q){ ((_Float16*)yp)[r] = (_Float16)yreg; ySh[r] = yreg; }
            }
        }
        __syncthreads();
    };

    // ---- projection (fp32, threads 0..255, overlapped with S1's interval) ----
    auto proj = [&](int stp) {
        if (t < 256){
            const float4* rr = (const float4*)(RSh + prow*68 + poct*8);
            const float4* yy = (const float4*)(ySh + poct*8);
            float pacc = 0.f;
            DOT4(pacc, rr[0], yy[0]); DOT4(pacc, rr[1], yy[1]);
            pacc += dpp_xor1(pacc);
            pacc += dpp_xor2(pacc);
            pacc += dpp_hmir(pacc);
            if (!poct) out[(size_t)(b*TT + stp)*OUTD + prow] = tanh_f(pacc + rbp);
        }
    };

    // ---- Heun scan ----
    for (int step=0; step<NSTEP; ++step) {
        proj(step);
        const int w = step >> 3;
        S0=slopesSh[w][0]; S1=slopesSh[w][1]; S2=slopesSh[w][2];
        S3=slopesSh[w][3]; S4=slopesSh[w][4]; S5=slopesSh[w][5];
        const float dtc = dtsSh[step];
        Feval(yp,  true,  dtc);
        Feval(y2p, false, dtc);
    }
    proj(NSTEP);
}

extern "C" void kernel_launch(void* const* d_in, const int* in_sizes, int n_in,
                              void* d_out, int out_size, void* d_ws, size_t ws_size,
                              hipStream_t stream) {
    const float* ts = (const float*)d_in[0];
    const float* x  = (const float*)d_in[1];
    const float* W0 = (const float*)d_in[2];
    const float* b0 = (const float*)d_in[3];
    const float* W1 = (const float*)d_in[4];
    const float* b1 = (const float*)d_in[5];
    const float* W2 = (const float*)d_in[6];
    const float* b2 = (const float*)d_in[7];
    const float* V0 = (const float*)d_in[8];
    const float* c0 = (const float*)d_in[9];
    const float* V1 = (const float*)d_in[10];
    const float* c1 = (const float*)d_in[11];
    const float* V2 = (const float*)d_in[12];
    const float* c2 = (const float*)d_in[13];
    const float* R  = (const float*)d_in[14];
    const float* rb = (const float*)d_in[15];
    float* out = (float*)d_out;

    ncde_solve<<<dim3(BB), dim3(512), 0, stream>>>(
        ts, x, W0, b0, W1, b1, W2, b2, V0, c0, V1, c1, V2, c2, R, rb, out);
}

// Round 11
// 596.874 us; speedup vs baseline: 1.4583x; 1.1594x over previous
//
#include <hip/hip_runtime.h>
#include <math.h>

// Problem constants: D=3, H=64, WIN=8, OUT=32, B=128, T=129
#define BB 128
#define TT 129
#define NSTEP 128
#define NW 16
#define WINW 8
#define OUTD 32

typedef _Float16 h2_t __attribute__((ext_vector_type(2)));

__device__ __forceinline__ float fast_rcp(float v){ return __builtin_amdgcn_rcpf(v); }
__device__ __forceinline__ float tanh_f(float v){
    float ax=fminf(fabsf(v),15.f); float e=__expf(2.f*ax);
    float r=1.f-2.f*fast_rcp(e+1.f); return copysignf(r,v);
}
// fused softplus+sigmoid sharing one exp (saves a transcendental on the critical path)
__device__ __forceinline__ void sigsp(float z, float& sp, float& sig){
    float e  = __expf(-fabsf(z));
    float rc = fast_rcp(1.f+e);
    sp  = fmaxf(z,0.f) + __logf(1.f+e);
    sig = (z>=0.f) ? rc : e*rc;
}
__device__ __forceinline__ float pack2(float a,float b){
    h2_t h; h.x=(_Float16)a; h.y=(_Float16)b; return __builtin_bit_cast(float,h);
}
__device__ __forceinline__ float dot2c(float wc,float ac,float acc){
    return __builtin_amdgcn_fdot2(__builtin_bit_cast(h2_t,wc),__builtin_bit_cast(h2_t,ac),acc,false);
}
__device__ __forceinline__ float dot2q(float4 wq,float4 aq,float acc){
    acc=dot2c(wq.x,aq.x,acc); acc=dot2c(wq.y,aq.y,acc);
    acc=dot2c(wq.z,aq.z,acc); acc=dot2c(wq.w,aq.w,acc); return acc;
}
#define DOT4(acc,Wv,Av) acc += (Wv).x*(Av).x + (Wv).y*(Av).y + (Wv).z*(Av).z + (Wv).w*(Av).w
#define PIN4(v) asm volatile("" : "+v"((v).x), "+v"((v).y), "+v"((v).z), "+v"((v).w))

// DPP cross-lane (VALU-speed).
#define DPPF(x,ctrl) __builtin_bit_cast(float, __builtin_amdgcn_update_dpp(0, __builtin_bit_cast(int,(x)), (ctrl), 0xF, 0xF, true))
__device__ __forceinline__ float dpp_xor1(float x){ return DPPF(x,0xB1); }   // quad_perm [1,0,3,2]
__device__ __forceinline__ float dpp_xor2(float x){ return DPPF(x,0x4E); }   // quad_perm [2,3,0,1]
__device__ __forceinline__ float dpp_hmir(float x){ return DPPF(x,0x141); }  // row_half_mirror
#define RED4(x) do{ x += dpp_xor1(x); x += dpp_xor2(x); }while(0)

// 512 threads, quad-split, ONE row per slot: r = t>>2 in [0,128), q = t&3 owns K-slice.
// Same total work as the 256-thread quad kernel (1600 dots, 2-DPP reduces, x4 transc.)
// but spread over 8 waves = 2 waves/SIMD -> latency-filled, thin stages.
// S6+S7 stay fused + lane-local on threads<256 (rows {r,64+r,128+r} V2 slices resident).
__global__ __launch_bounds__(512, 1)
void ncde_solve(const float* __restrict__ ts, const float* __restrict__ x,
                const float* __restrict__ W0, const float* __restrict__ b0,
                const float* __restrict__ W1, const float* __restrict__ b1,
                const float* __restrict__ W2, const float* __restrict__ b2,
                const float* __restrict__ V0, const float* __restrict__ c0,
                const float* __restrict__ V1, const float* __restrict__ c1,
                const float* __restrict__ V2, const float* __restrict__ c2,
                const float* __restrict__ R, const float* __restrict__ rb,
                float* __restrict__ out)
{
    const int b = blockIdx.x;
    const int t = threadIdx.x;           // 0..511
    const int r = t >> 2, q = t & 3;     // row slot [0,128), K-slice
    const int rl = r & 63;
    const int pt = (t >= 256) ? (t - 256) : 0;   // projection thread id (threads 256..511)
    const int prow = pt >> 3, poct = pt & 7;

    __shared__ __align__(16) float RSh[OUTD*68];
    __shared__ __align__(16) float ySh[64];
    __shared__ __align__(16) float yp[32], y2p[32];      // 64 halves each
    __shared__ __align__(16) float a0H[64], a1H[64];     // 128 halves each
    __shared__ __align__(16) float mpH[96];              // 192 halves (d-major 3x64)
    __shared__ __align__(16) float u0H[192], u1H[192];   // 3x128 halves; fp32 scratch in init
    __shared__ float mF32[64];                            // fp32 m[64+h] for S7
    __shared__ float slopesSh[NW][6];
    __shared__ float dtsSh[NSTEP];

    // ---- fp16-packed quad-slice weight carriers ----
    // v0: row r (2 f4) ; v1: row r (4 f4) ; v2: rows rl, 64+rl, 128+rl (12 f4)
    float4 v0c[2], v1c[4], v2c[3][4];
    {
        auto pkld = [](const float* src)->float4{
            const float4* p=(const float4*)src;
            float4 a=p[0], c=p[1];
            float4 rr; rr.x=pack2(a.x,a.y); rr.y=pack2(a.z,a.w); rr.z=pack2(c.x,c.y); rr.w=pack2(c.z,c.w);
            return rr;
        };
        {
            const float* base = V0 + r*64 + q*16;
            v0c[0]=pkld(base); v0c[1]=pkld(base+8);
        }
        {
            const float* base = V1 + r*128 + q*32;
            #pragma unroll
            for (int k=0;k<4;k++) v1c[k]=pkld(base+8*k);
        }
        #pragma unroll
        for (int i=0;i<3;i++){
            const float* base = V2 + (rl+64*i)*128 + q*32;
            #pragma unroll
            for (int k=0;k<4;k++) v2c[i][k]=pkld(base+8*k);
        }
        PIN4(v0c[0]); PIN4(v0c[1]);
        #pragma unroll
        for (int k=0;k<4;k++) PIN4(v1c[k]);
        #pragma unroll
        for (int i=0;i<3;i++){
            #pragma unroll
            for (int k=0;k<4;k++) PIN4(v2c[i][k]);
        }
    }
    const float c0r=c0[r], c1r=c1[r];
    const float c2a=c2[rl], c2b=c2[64+rl], c2c=c2[128+rl];
    const float rbp = rb[prow & 31];

    for (int i=t; i<OUTD*64; i+=512) RSh[(i>>6)*68 + (i&63)] = R[i];
    const float* tsb = ts + (size_t)b*TT;
    if (t < NSTEP) dtsSh[t] = tsb[t+1] - tsb[t];

    // ---- log-signature slopes (threads 0..15) ----
    if (t < NW) {
        const int w = t;
        const float* xs = x + (size_t)(b*TT + w*WINW)*3;
        float x0c[3] = {xs[0], xs[1], xs[2]};
        float prev[3] = {x0c[0], x0c[1], x0c[2]};
        float am01=0.f, am02=0.f, am12=0.f, am10=0.f, am20=0.f, am21=0.f;
        #pragma unroll
        for (int k=0;k<WINW;k++) {
            float cur[3] = {xs[(k+1)*3+0], xs[(k+1)*3+1], xs[(k+1)*3+2]};
            float rel[3], dv[3];
            #pragma unroll
            for (int c=0;c<3;c++){ rel[c]=prev[c]-x0c[c]; dv[c]=cur[c]-prev[c]; }
            am01 += rel[0]*dv[1]; am10 += rel[1]*dv[0];
            am02 += rel[0]*dv[2]; am20 += rel[2]*dv[0];
            am12 += rel[1]*dv[2]; am21 += rel[2]*dv[1];
            prev[0]=cur[0]; prev[1]=cur[1]; prev[2]=cur[2];
        }
        const float invden = 1.f/(tsb[(w+1)*WINW] - tsb[w*WINW]);
        slopesSh[w][0] = (prev[0]-x0c[0])*invden;
        slopesSh[w][1] = (prev[1]-x0c[1])*invden;
        slopesSh[w][2] = (prev[2]-x0c[2])*invden;
        slopesSh[w][3] = 0.5f*(am01-am10)*invden;
        slopesSh[w][4] = 0.5f*(am02-am20)*invden;
        slopesSh[w][5] = 0.5f*(am12-am21)*invden;
    }

    // ---- h0 = init_mlp(x[b,0,:]) fp32 (u0H/u1H as scratch) ----
    if (t < 128) {
        const float xv0 = x[(size_t)b*TT*3+0];
        const float xv1 = x[(size_t)b*TT*3+1];
        const float xv2 = x[(size_t)b*TT*3+2];
        float acc = b0[t] + W0[t*3]*xv0 + W0[t*3+1]*xv1 + W0[t*3+2]*xv2;
        float sp, sg; sigsp(acc, sp, sg);
        u0H[t] = sp;
    }
    __syncthreads();
    if (t < 128) {
        float acc = b1[t];
        const float4* rw = (const float4*)(W1 + t*128);
        #pragma unroll 8
        for (int k=0;k<32;k++){ float4 wv=rw[k]; float4 av=*(const float4*)&u0H[4*k]; DOT4(acc,wv,av); }
        float sp, sg; sigsp(acc, sp, sg);
        u1H[t] = sp;
    }
    __syncthreads();
    if (t < 64) {
        float acc = b2[t];
        const float4* rw = (const float4*)(W2 + t*128);
        #pragma unroll 8
        for (int k=0;k<32;k++){ float4 wv=rw[k]; float4 av=*(const float4*)&u1H[4*k]; DOT4(acc,wv,av); }
        ySh[t] = acc;
        ((_Float16*)yp)[t] = (_Float16)acc;
    }
    __syncthreads();

    float yreg = (r < 64) ? ySh[r] : 0.f;   // y-state lives in threads<256 (quad-redundant)
    float k1r = 0.f;
    float S0,S1,S2,S3,S4,S5;

    auto Feval = [&](const float* ypIn, bool first, float dtc) {
        float sig0r, sig1r, mA=0.f, mC=0.f;
        // S1: z0 = V0@y + c0 (row r)
        {
            const float4* Y = (const float4*)ypIn;
            float z = dot2q(v0c[0], Y[q*2], 0.f);
            z = dot2q(v0c[1], Y[q*2+1], z);
            RED4(z); z += c0r;
            float sp; sigsp(z, sp, sig0r);
            if (!q) ((_Float16*)a0H)[r] = (_Float16)sp;
        }
        __syncthreads();
        // S2: z1 = V1@a0 + c1 (row r)
        {
            const float4* A = (const float4*)a0H + q*4;
            float z = 0.f;
            #pragma unroll
            for (int k=0;k<4;k++) z = dot2q(v1c[k], A[k], z);
            RED4(z); z += c1r;
            float sp; sigsp(z, sp, sig1r);
            if (!q) ((_Float16*)a1H)[r] = (_Float16)sp;
        }
        __syncthreads();
        // S3: m = tanh(V2@a1 + c2). Slots <64: rows rl & 128+rl. Slots >=64: row 64+rl.
        {
            const float4* A = (const float4*)a1H + q*4;
            float4 a0=A[0],a1=A[1],a2=A[2],a3=A[3];
            if (r < 64){
                float zA=dot2q(v2c[0][0],a0,0.f); zA=dot2q(v2c[0][1],a1,zA); zA=dot2q(v2c[0][2],a2,zA); zA=dot2q(v2c[0][3],a3,zA);
                float zC=dot2q(v2c[2][0],a0,0.f); zC=dot2q(v2c[2][1],a1,zC); zC=dot2q(v2c[2][2],a2,zC); zC=dot2q(v2c[2][3],a3,zC);
                RED4(zA); RED4(zC);
                mA = tanh_f(zA + c2a); mC = tanh_f(zC + c2c);
                if (!q){
                    ((_Float16*)mpH)[rl]     = (_Float16)mA;
                    ((_Float16*)mpH)[128+rl] = (_Float16)mC;
                }
            } else {
                float zB=dot2q(v2c[1][0],a0,0.f); zB=dot2q(v2c[1][1],a1,zB); zB=dot2q(v2c[1][2],a2,zB); zB=dot2q(v2c[1][3],a3,zB);
                RED4(zB);
                float mB = tanh_f(zB + c2b);
                if (!q){
                    ((_Float16*)mpH)[64+rl] = (_Float16)mB;
                    mF32[rl] = mB;
                }
            }
        }
        __syncthreads();
        // S4: u0[d] = sig0 ⊙ (V0 @ m[d]) (row r, 3 tangents)
        {
            const float4* M = (const float4*)mpH;
            float4 g0a=M[q*2],    g0b=M[q*2+1];
            float4 g1a=M[8+q*2],  g1b=M[8+q*2+1];
            float4 g2a=M[16+q*2], g2b=M[16+q*2+1];
            float t0=dot2q(v0c[0],g0a,0.f); t0=dot2q(v0c[1],g0b,t0);
            float t1=dot2q(v0c[0],g1a,0.f); t1=dot2q(v0c[1],g1b,t1);
            float t2=dot2q(v0c[0],g2a,0.f); t2=dot2q(v0c[1],g2b,t2);
            RED4(t0); RED4(t1); RED4(t2);
            if (!q){
                ((_Float16*)u0H)[r]     = (_Float16)(sig0r*t0);
                ((_Float16*)u0H)[128+r] = (_Float16)(sig0r*t1);
                ((_Float16*)u0H)[256+r] = (_Float16)(sig0r*t2);
            }
        }
        __syncthreads();
        // S5: u1[d] = sig1 ⊙ (V1 @ u0[d]) (row r, 3 tangents)
        {
            const float4* U = (const float4*)u0H;
            float t0=0.f,t1=0.f,t2=0.f;
            #pragma unroll
            for (int k=0;k<4;k++){
                float4 w = v1c[k];
                t0=dot2q(w,U[q*4+k],t0); t1=dot2q(w,U[16+q*4+k],t1); t2=dot2q(w,U[32+q*4+k],t2);
            }
            RED4(t0); RED4(t1); RED4(t2);
            if (!q){
                ((_Float16*)u1H)[r]     = (_Float16)(sig1r*t0);
                ((_Float16*)u1H)[128+r] = (_Float16)(sig1r*t1);
                ((_Float16*)u1H)[256+r] = (_Float16)(sig1r*t2);
            }
        }
        __syncthreads();
        // S6+S7 fused (threads<256 only): rows {rl,64+rl,128+rl} x skip-diagonal tangents,
        // all lane-local; mB via fp32 side-channel. Heun update in-register.
        if (r < 64){
            const float4* U = (const float4*)u1H;
            float4 g0[4],g1[4],g2[4];
            #pragma unroll
            for (int k=0;k<4;k++){ g0[k]=U[q*4+k]; g1[k]=U[16+q*4+k]; g2[k]=U[32+q*4+k]; }
            float J1r=0.f,J2r=0.f,J0m=0.f,J2m=0.f,J0t=0.f,J1t=0.f;
            #pragma unroll
            for (int k=0;k<4;k++){
                float4 wa=v2c[0][k], wb=v2c[1][k], wc=v2c[2][k];
                J1r=dot2q(wa,g1[k],J1r); J2r=dot2q(wa,g2[k],J2r);
                J0m=dot2q(wb,g0[k],J0m); J2m=dot2q(wb,g2[k],J2m);
                J0t=dot2q(wc,g0[k],J0t); J1t=dot2q(wc,g1[k],J1t);
            }
            RED4(J1r); RED4(J2r); RED4(J0m); RED4(J2m); RED4(J0t); RED4(J1t);
            const float mB = mF32[rl];
            const float dtA = 1.f-mA*mA, dtB = 1.f-mB*mB, dtC = 1.f-mC*mC;
            J1r*=dtA; J2r*=dtA; J0m*=dtB; J2m*=dtB; J0t*=dtC; J1t*=dtC;
            float kk = mA*S0 + mB*S1 + mC*S2
                     + S3*(J0m - J1r) + S4*(J0t - J2r) + S5*(J1t - J2m);
            if (first){
                k1r = kk;
                float y2 = yreg + dtc*kk;
                if (!q) ((_Float16*)y2p)[rl] = (_Float16)y2;
            } else {
                yreg += 0.5f*dtc*(k1r + kk);
                if (!q){ ((_Float16*)yp)[rl] = (_Float16)yreg; ySh[rl] = yreg; }
            }
        }
        __syncthreads();
    };

    // ---- projection (threads 256..511 — balances their lighter S3/S6 load) ----
    auto proj = [&](int stp) {
        if (t >= 256){
            const float4* rr = (const float4*)(RSh + prow*68 + poct*8);
            const float4* yy = (const float4*)(ySh + poct*8);
            float pacc = 0.f;
            DOT4(pacc, rr[0], yy[0]); DOT4(pacc, rr[1], yy[1]);
            pacc += dpp_xor1(pacc);
            pacc += dpp_xor2(pacc);
            pacc += dpp_hmir(pacc);
            if (!poct) out[(size_t)(b*TT + stp)*OUTD + prow] = tanh_f(pacc + rbp);
        }
    };

    // ---- Heun scan ----
    for (int step=0; step<NSTEP; ++step) {
        proj(step);
        const int w = step >> 3;
        S0=slopesSh[w][0]; S1=slopesSh[w][1]; S2=slopesSh[w][2];
        S3=slopesSh[w][3]; S4=slopesSh[w][4]; S5=slopesSh[w][5];
        const float dtc = dtsSh[step];
        Feval(yp,  true,  dtc);
        Feval(y2p, false, dtc);
    }
    proj(NSTEP);
}

extern "C" void kernel_launch(void* const* d_in, const int* in_sizes, int n_in,
                              void* d_out, int out_size, void* d_ws, size_t ws_size,
                              hipStream_t stream) {
    const float* ts = (const float*)d_in[0];
    const float* x  = (const float*)d_in[1];
    const float* W0 = (const float*)d_in[2];
    const float* b0 = (const float*)d_in[3];
    const float* W1 = (const float*)d_in[4];
    const float* b1 = (const float*)d_in[5];
    const float* W2 = (const float*)d_in[6];
    const float* b2 = (const float*)d_in[7];
    const float* V0 = (const float*)d_in[8];
    const float* c0 = (const float*)d_in[9];
    const float* V1 = (const float*)d_in[10];
    const float* c1 = (const float*)d_in[11];
    const float* V2 = (const float*)d_in[12];
    const float* c2 = (const float*)d_in[13];
    const float* R  = (const float*)d_in[14];
    const float* rb = (const float*)d_in[15];
    float* out = (float*)d_out;

    ncde_solve<<<dim3(BB), dim3(512), 0, stream>>>(
        ts, x, W0, b0, W1, b1, W2, b2, V0, c0, V1, c1, V2, c2, R, rb, out);
}

// Round 12
// 590.936 us; speedup vs baseline: 1.4730x; 1.0100x over previous
//
#include <hip/hip_runtime.h>
#include <math.h>

// Problem constants: D=3, H=64, WIN=8, OUT=32, B=128, T=129
#define BB 128
#define TT 129
#define NSTEP 128
#define NW 16
#define WINW 8
#define OUTD 32

typedef _Float16 h2_t __attribute__((ext_vector_type(2)));

__device__ __forceinline__ float fast_rcp(float v){ return __builtin_amdgcn_rcpf(v); }
__device__ __forceinline__ float tanh_f(float v){
    float ax=fminf(fabsf(v),15.f); float e=__expf(2.f*ax);
    float r=1.f-2.f*fast_rcp(e+1.f); return copysignf(r,v);
}
// fused softplus+sigmoid sharing one exp
__device__ __forceinline__ void sigsp(float z, float& sp, float& sig){
    float e  = __expf(-fabsf(z));
    float rc = fast_rcp(1.f+e);
    sp  = fmaxf(z,0.f) + __logf(1.f+e);
    sig = (z>=0.f) ? rc : e*rc;
}
__device__ __forceinline__ float pack2(float a,float b){
    h2_t h; h.x=(_Float16)a; h.y=(_Float16)b; return __builtin_bit_cast(float,h);
}
__device__ __forceinline__ float dot2c(float wc,float ac,float acc){
    return __builtin_amdgcn_fdot2(__builtin_bit_cast(h2_t,wc),__builtin_bit_cast(h2_t,ac),acc,false);
}
__device__ __forceinline__ float dot2q(float4 wq,float4 aq,float acc){
    acc=dot2c(wq.x,aq.x,acc); acc=dot2c(wq.y,aq.y,acc);
    acc=dot2c(wq.z,aq.z,acc); acc=dot2c(wq.w,aq.w,acc); return acc;
}
#define DOT4(acc,Wv,Av) acc += (Wv).x*(Av).x + (Wv).y*(Av).y + (Wv).z*(Av).z + (Wv).w*(Av).w
#define PIN4(v) asm volatile("" : "+v"((v).x), "+v"((v).y), "+v"((v).z), "+v"((v).w))

// DPP cross-lane (VALU-speed).
#define DPPF(x,ctrl) __builtin_bit_cast(float, __builtin_amdgcn_update_dpp(0, __builtin_bit_cast(int,(x)), (ctrl), 0xF, 0xF, true))
__device__ __forceinline__ float dpp_xor1(float x){ return DPPF(x,0xB1); }   // quad_perm [1,0,3,2]
__device__ __forceinline__ float dpp_xor2(float x){ return DPPF(x,0x4E); }   // quad_perm [2,3,0,1]
__device__ __forceinline__ float dpp_hmir(float x){ return DPPF(x,0x141); }  // row_half_mirror
#define RED4(x) do{ x += dpp_xor1(x); x += dpp_xor2(x); }while(0)

// 512 threads, quad-split, one row per slot: r=t>>2 in [0,128), q=t&3 K-slice.
// w-trick: S5 pre-contracts u1[d] with the slope coefficients into w0,w1,w2
// (lane-local FMAs), so S6 does 3 row-dots instead of 6 and S7 collapses to
// kk = m.S - dtA*D0 + dtB*D1 + dtC*D2.
__global__ __launch_bounds__(512, 1)
void ncde_solve(const float* __restrict__ ts, const float* __restrict__ x,
                const float* __restrict__ W0, const float* __restrict__ b0,
                const float* __restrict__ W1, const float* __restrict__ b1,
                const float* __restrict__ W2, const float* __restrict__ b2,
                const float* __restrict__ V0, const float* __restrict__ c0,
                const float* __restrict__ V1, const float* __restrict__ c1,
                const float* __restrict__ V2, const float* __restrict__ c2,
                const float* __restrict__ R, const float* __restrict__ rb,
                float* __restrict__ out)
{
    const int b = blockIdx.x;
    const int t = threadIdx.x;           // 0..511
    const int r = t >> 2, q = t & 3;     // row slot [0,128), K-slice
    const int rl = r & 63;
    const int pt = (t >= 256) ? (t - 256) : 0;   // projection thread id (threads 256..511)
    const int prow = pt >> 3, poct = pt & 7;

    __shared__ __align__(16) float RSh[OUTD*68];
    __shared__ __align__(16) float ySh[64];
    __shared__ __align__(16) float yp[32], y2p[32];      // 64 halves each
    __shared__ __align__(16) float a0H[64], a1H[64];     // 128 halves each
    __shared__ __align__(16) float mpH[96];              // 192 halves (d-major 3x64)
    __shared__ __align__(16) float u0H[192], wH[192];    // 3x128 halves; fp32 scratch in init
    __shared__ float mF32[64];                            // fp32 m[64+h] for S7
    __shared__ float slopesSh[NW][6];
    __shared__ float dtsSh[NSTEP];

    // ---- fp16-packed quad-slice weight carriers ----
    float4 v0c[2], v1c[4], v2c[3][4];
    {
        auto pkld = [](const float* src)->float4{
            const float4* p=(const float4*)src;
            float4 a=p[0], c=p[1];
            float4 rr; rr.x=pack2(a.x,a.y); rr.y=pack2(a.z,a.w); rr.z=pack2(c.x,c.y); rr.w=pack2(c.z,c.w);
            return rr;
        };
        {
            const float* base = V0 + r*64 + q*16;
            v0c[0]=pkld(base); v0c[1]=pkld(base+8);
        }
        {
            const float* base = V1 + r*128 + q*32;
            #pragma unroll
            for (int k=0;k<4;k++) v1c[k]=pkld(base+8*k);
        }
        #pragma unroll
        for (int i=0;i<3;i++){
            const float* base = V2 + (rl+64*i)*128 + q*32;
            #pragma unroll
            for (int k=0;k<4;k++) v2c[i][k]=pkld(base+8*k);
        }
        PIN4(v0c[0]); PIN4(v0c[1]);
        #pragma unroll
        for (int k=0;k<4;k++) PIN4(v1c[k]);
        #pragma unroll
        for (int i=0;i<3;i++){
            #pragma unroll
            for (int k=0;k<4;k++) PIN4(v2c[i][k]);
        }
    }
    const float c0r=c0[r], c1r=c1[r];
    const float c2a=c2[rl], c2b=c2[64+rl], c2c=c2[128+rl];
    const float rbp = rb[prow & 31];

    for (int i=t; i<OUTD*64; i+=512) RSh[(i>>6)*68 + (i&63)] = R[i];
    const float* tsb = ts + (size_t)b*TT;
    if (t < NSTEP) dtsSh[t] = tsb[t+1] - tsb[t];

    // ---- log-signature slopes (threads 0..15) ----
    if (t < NW) {
        const int w = t;
        const float* xs = x + (size_t)(b*TT + w*WINW)*3;
        float x0c[3] = {xs[0], xs[1], xs[2]};
        float prev[3] = {x0c[0], x0c[1], x0c[2]};
        float am01=0.f, am02=0.f, am12=0.f, am10=0.f, am20=0.f, am21=0.f;
        #pragma unroll
        for (int k=0;k<WINW;k++) {
            float cur[3] = {xs[(k+1)*3+0], xs[(k+1)*3+1], xs[(k+1)*3+2]};
            float rel[3], dv[3];
            #pragma unroll
            for (int c=0;c<3;c++){ rel[c]=prev[c]-x0c[c]; dv[c]=cur[c]-prev[c]; }
            am01 += rel[0]*dv[1]; am10 += rel[1]*dv[0];
            am02 += rel[0]*dv[2]; am20 += rel[2]*dv[0];
            am12 += rel[1]*dv[2]; am21 += rel[2]*dv[1];
            prev[0]=cur[0]; prev[1]=cur[1]; prev[2]=cur[2];
        }
        const float invden = 1.f/(tsb[(w+1)*WINW] - tsb[w*WINW]);
        slopesSh[w][0] = (prev[0]-x0c[0])*invden;
        slopesSh[w][1] = (prev[1]-x0c[1])*invden;
        slopesSh[w][2] = (prev[2]-x0c[2])*invden;
        slopesSh[w][3] = 0.5f*(am01-am10)*invden;
        slopesSh[w][4] = 0.5f*(am02-am20)*invden;
        slopesSh[w][5] = 0.5f*(am12-am21)*invden;
    }

    // ---- h0 = init_mlp(x[b,0,:]) fp32 (u0H/wH as scratch) ----
    if (t < 128) {
        const float xv0 = x[(size_t)b*TT*3+0];
        const float xv1 = x[(size_t)b*TT*3+1];
        const float xv2 = x[(size_t)b*TT*3+2];
        float acc = b0[t] + W0[t*3]*xv0 + W0[t*3+1]*xv1 + W0[t*3+2]*xv2;
        float sp, sg; sigsp(acc, sp, sg);
        u0H[t] = sp;
    }
    __syncthreads();
    if (t < 128) {
        float acc = b1[t];
        const float4* rw = (const float4*)(W1 + t*128);
        #pragma unroll 8
        for (int k=0;k<32;k++){ float4 wv=rw[k]; float4 av=*(const float4*)&u0H[4*k]; DOT4(acc,wv,av); }
        float sp, sg; sigsp(acc, sp, sg);
        wH[t] = sp;
    }
    __syncthreads();
    if (t < 64) {
        float acc = b2[t];
        const float4* rw = (const float4*)(W2 + t*128);
        #pragma unroll 8
        for (int k=0;k<32;k++){ float4 wv=rw[k]; float4 av=*(const float4*)&wH[4*k]; DOT4(acc,wv,av); }
        ySh[t] = acc;
        ((_Float16*)yp)[t] = (_Float16)acc;
    }
    __syncthreads();

    float yreg = (r < 64) ? ySh[r] : 0.f;   // y-state in threads<256 (quad-redundant)
    float k1r = 0.f;
    float S0,S1,S2,S3,S4,S5;

    auto Feval = [&](const float* ypIn, bool first, float dtc) {
        float sig0r, sig1r, mA=0.f, mC=0.f;
        // S1: z0 = V0@y + c0 (row r)
        {
            const float4* Y = (const float4*)ypIn;
            float za = dot2q(v0c[0], Y[q*2], 0.f);
            float zb = dot2q(v0c[1], Y[q*2+1], 0.f);
            float z = za + zb;
            RED4(z); z += c0r;
            float sp; sigsp(z, sp, sig0r);
            if (!q) ((_Float16*)a0H)[r] = (_Float16)sp;
        }
        __syncthreads();
        // S2: z1 = V1@a0 + c1 (row r) — split accumulator chain
        {
            const float4* A = (const float4*)a0H + q*4;
            float za = dot2q(v1c[0], A[0], 0.f); za = dot2q(v1c[1], A[1], za);
            float zb = dot2q(v1c[2], A[2], 0.f); zb = dot2q(v1c[3], A[3], zb);
            float z = za + zb;
            RED4(z); z += c1r;
            float sp; sigsp(z, sp, sig1r);
            if (!q) ((_Float16*)a1H)[r] = (_Float16)sp;
        }
        __syncthreads();
        // S3: m = tanh(V2@a1 + c2). Slots <64: rows rl & 128+rl. Slots >=64: row 64+rl.
        {
            const float4* A = (const float4*)a1H + q*4;
            float4 a0=A[0],a1=A[1],a2=A[2],a3=A[3];
            if (r < 64){
                float zAa=dot2q(v2c[0][0],a0,0.f); zAa=dot2q(v2c[0][1],a1,zAa);
                float zAb=dot2q(v2c[0][2],a2,0.f); zAb=dot2q(v2c[0][3],a3,zAb);
                float zCa=dot2q(v2c[2][0],a0,0.f); zCa=dot2q(v2c[2][1],a1,zCa);
                float zCb=dot2q(v2c[2][2],a2,0.f); zCb=dot2q(v2c[2][3],a3,zCb);
                float zA=zAa+zAb, zC=zCa+zCb;
                RED4(zA); RED4(zC);
                mA = tanh_f(zA + c2a); mC = tanh_f(zC + c2c);
                if (!q){
                    ((_Float16*)mpH)[rl]     = (_Float16)mA;
                    ((_Float16*)mpH)[128+rl] = (_Float16)mC;
                }
            } else {
                float zBa=dot2q(v2c[1][0],a0,0.f); zBa=dot2q(v2c[1][1],a1,zBa);
                float zBb=dot2q(v2c[1][2],a2,0.f); zBb=dot2q(v2c[1][3],a3,zBb);
                float zB=zBa+zBb;
                RED4(zB);
                float mB = tanh_f(zB + c2b);
                if (!q){
                    ((_Float16*)mpH)[64+rl] = (_Float16)mB;
                    mF32[rl] = mB;
                }
            }
        }
        __syncthreads();
        // S4: u0[d] = sig0 ⊙ (V0 @ m[d]) (row r, 3 tangents)
        {
            const float4* M = (const float4*)mpH;
            float4 g0a=M[q*2],    g0b=M[q*2+1];
            float4 g1a=M[8+q*2],  g1b=M[8+q*2+1];
            float4 g2a=M[16+q*2], g2b=M[16+q*2+1];
            float t0=dot2q(v0c[0],g0a,0.f); t0=dot2q(v0c[1],g0b,t0);
            float t1=dot2q(v0c[0],g1a,0.f); t1=dot2q(v0c[1],g1b,t1);
            float t2=dot2q(v0c[0],g2a,0.f); t2=dot2q(v0c[1],g2b,t2);
            RED4(t0); RED4(t1); RED4(t2);
            if (!q){
                ((_Float16*)u0H)[r]     = (_Float16)(sig0r*t0);
                ((_Float16*)u0H)[128+r] = (_Float16)(sig0r*t1);
                ((_Float16*)u0H)[256+r] = (_Float16)(sig0r*t2);
            }
        }
        __syncthreads();
        // S5: u1[d] = sig1 ⊙ (V1 @ u0[d]) then pre-contract into w0,w1,w2 (lane-local):
        //   w0 = sig1*(S3*t1 + S4*t2) ; w1 = sig1*(S3*t0 - S5*t2) ; w2 = sig1*(S4*t0 + S5*t1)
        {
            const float4* U = (const float4*)u0H;
            float t0a=0.f,t0b=0.f,t1a=0.f,t1b=0.f,t2a=0.f,t2b=0.f;
            #pragma unroll
            for (int k=0;k<2;k++){
                float4 w = v1c[k];
                t0a=dot2q(w,U[q*4+k],t0a); t1a=dot2q(w,U[16+q*4+k],t1a); t2a=dot2q(w,U[32+q*4+k],t2a);
            }
            #pragma unroll
            for (int k=2;k<4;k++){
                float4 w = v1c[k];
                t0b=dot2q(w,U[q*4+k],t0b); t1b=dot2q(w,U[16+q*4+k],t1b); t2b=dot2q(w,U[32+q*4+k],t2b);
            }
            float t0=t0a+t0b, t1=t1a+t1b, t2=t2a+t2b;
            RED4(t0); RED4(t1); RED4(t2);
            if (!q){
                float w0 = sig1r*(S3*t1 + S4*t2);
                float w1 = sig1r*(S3*t0 - S5*t2);
                float w2 = sig1r*(S4*t0 + S5*t1);
                ((_Float16*)wH)[r]     = (_Float16)w0;
                ((_Float16*)wH)[128+r] = (_Float16)w1;
                ((_Float16*)wH)[256+r] = (_Float16)w2;
            }
        }
        __syncthreads();
        // S6+S7 fused (threads<256): D_b = V2[row_b] @ w_b, 3 dots (w-trick), all lane-local.
        if (r < 64){
            const float4* W = (const float4*)wH;
            float D0a=dot2q(v2c[0][0],W[q*4+0],0.f);   D0a=dot2q(v2c[0][1],W[q*4+1],D0a);
            float D0b=dot2q(v2c[0][2],W[q*4+2],0.f);   D0b=dot2q(v2c[0][3],W[q*4+3],D0b);
            float D1a=dot2q(v2c[1][0],W[16+q*4+0],0.f);D1a=dot2q(v2c[1][1],W[16+q*4+1],D1a);
            float D1b=dot2q(v2c[1][2],W[16+q*4+2],0.f);D1b=dot2q(v2c[1][3],W[16+q*4+3],D1b);
            float D2a=dot2q(v2c[2][0],W[32+q*4+0],0.f);D2a=dot2q(v2c[2][1],W[32+q*4+1],D2a);
            float D2b=dot2q(v2c[2][2],W[32+q*4+2],0.f);D2b=dot2q(v2c[2][3],W[32+q*4+3],D2b);
            float D0=D0a+D0b, D1=D1a+D1b, D2=D2a+D2b;
            RED4(D0); RED4(D1); RED4(D2);
            const float mB = mF32[rl];
            const float dtA = 1.f-mA*mA, dtB = 1.f-mB*mB, dtC = 1.f-mC*mC;
            float kk = mA*S0 + mB*S1 + mC*S2 - dtA*D0 + dtB*D1 + dtC*D2;
            if (first){
                k1r = kk;
                float y2 = yreg + dtc*kk;
                if (!q) ((_Float16*)y2p)[rl] = (_Float16)y2;
            } else {
                yreg += 0.5f*dtc*(k1r + kk);
                if (!q){ ((_Float16*)yp)[rl] = (_Float16)yreg; ySh[rl] = yreg; }
            }
        }
        __syncthreads();
    };

    // ---- projection (threads 256..511) ----
    auto proj = [&](int stp) {
        if (t >= 256){
            const float4* rr = (const float4*)(RSh + prow*68 + poct*8);
            const float4* yy = (const float4*)(ySh + poct*8);
            float pacc = 0.f;
            DOT4(pacc, rr[0], yy[0]); DOT4(pacc, rr[1], yy[1]);
            pacc += dpp_xor1(pacc);
            pacc += dpp_xor2(pacc);
            pacc += dpp_hmir(pacc);
            if (!poct) out[(size_t)(b*TT + stp)*OUTD + prow] = tanh_f(pacc + rbp);
        }
    };

    // ---- Heun scan ----
    for (int step=0; step<NSTEP; ++step) {
        proj(step);
        const int w = step >> 3;
        S0=slopesSh[w][0]; S1=slopesSh[w][1]; S2=slopesSh[w][2];
        S3=slopesSh[w][3]; S4=slopesSh[w][4]; S5=slopesSh[w][5];
        const float dtc = dtsSh[step];
        Feval(yp,  true,  dtc);
        Feval(y2p, false, dtc);
    }
    proj(NSTEP);
}

extern "C" void kernel_launch(void* const* d_in, const int* in_sizes, int n_in,
                              void* d_out, int out_size, void* d_ws, size_t ws_size,
                              hipStream_t stream) {
    const float* ts = (const float*)d_in[0];
    const float* x  = (const float*)d_in[1];
    const float* W0 = (const float*)d_in[2];
    const float* b0 = (const float*)d_in[3];
    const float* W1 = (const float*)d_in[4];
    const float* b1 = (const float*)d_in[5];
    const float* W2 = (const float*)d_in[6];
    const float* b2 = (const float*)d_in[7];
    const float* V0 = (const float*)d_in[8];
    const float* c0 = (const float*)d_in[9];
    const float* V1 = (const float*)d_in[10];
    const float* c1 = (const float*)d_in[11];
    const float* V2 = (const float*)d_in[12];
    const float* c2 = (const float*)d_in[13];
    const float* R  = (const float*)d_in[14];
    const float* rb = (const float*)d_in[15];
    float* out = (float*)d_out;

    ncde_solve<<<dim3(BB), dim3(512), 0, stream>>>(
        ts, x, W0, b0, W1, b1, W2, b2, V0, c0, V1, c1, V2, c2, R, rb, out);
}

// Round 14
// 589.273 us; speedup vs baseline: 1.4771x; 1.0028x over previous
//
#include <hip/hip_runtime.h>
#include <math.h>

// Problem constants: D=3, H=64, WIN=8, OUT=32, B=128, T=129
#define BB 128
#define TT 129
#define NSTEP 128
#define NW 16
#define WINW 8
#define OUTD 32

typedef _Float16 h2_t __attribute__((ext_vector_type(2)));

__device__ __forceinline__ float fast_rcp(float v){ return __builtin_amdgcn_rcpf(v); }
__device__ __forceinline__ float tanh_f(float v){
    float ax=fminf(fabsf(v),15.f); float e=__expf(2.f*ax);
    float r=1.f-2.f*fast_rcp(e+1.f); return copysignf(r,v);
}
// fused softplus+sigmoid sharing one exp
__device__ __forceinline__ void sigsp(float z, float& sp, float& sig){
    float e  = __expf(-fabsf(z));
    float rc = fast_rcp(1.f+e);
    sp  = fmaxf(z,0.f) + __logf(1.f+e);
    sig = (z>=0.f) ? rc : e*rc;
}
__device__ __forceinline__ float pack2(float a,float b){
    h2_t h; h.x=(_Float16)a; h.y=(_Float16)b; return __builtin_bit_cast(float,h);
}
__device__ __forceinline__ float dot2c(float wc,float ac,float acc){
    return __builtin_amdgcn_fdot2(__builtin_bit_cast(h2_t,wc),__builtin_bit_cast(h2_t,ac),acc,false);
}
__device__ __forceinline__ float dot2q(float4 wq,float4 aq,float acc){
    acc=dot2c(wq.x,aq.x,acc); acc=dot2c(wq.y,aq.y,acc);
    acc=dot2c(wq.z,aq.z,acc); acc=dot2c(wq.w,aq.w,acc); return acc;
}
#define DOT4(acc,Wv,Av) acc += (Wv).x*(Av).x + (Wv).y*(Av).y + (Wv).z*(Av).z + (Wv).w*(Av).w
#define PIN4(v) asm volatile("" : "+v"((v).x), "+v"((v).y), "+v"((v).z), "+v"((v).w))

// DPP cross-lane (VALU-speed).
#define DPPF(x,ctrl) __builtin_bit_cast(float, __builtin_amdgcn_update_dpp(0, __builtin_bit_cast(int,(x)), (ctrl), 0xF, 0xF, true))
__device__ __forceinline__ float dpp_xor1(float x){ return DPPF(x,0xB1); }   // quad_perm [1,0,3,2]
__device__ __forceinline__ float dpp_xor2(float x){ return DPPF(x,0x4E); }   // quad_perm [2,3,0,1]
__device__ __forceinline__ float dpp_hmir(float x){ return DPPF(x,0x141); }  // row_half_mirror
#define RED4(x) do{ x += dpp_xor1(x); x += dpp_xor2(x); }while(0)

// 256 threads (4 waves — probe: barrier cost scales with wave count), quad-split:
// slot r = t>>2 in [0,64), q = t&3 owns K-slice. Slot r owns rows {r, 64+r} of V0/V1
// and rows {r, 64+r, 128+r} of V2 -> mA,mB,mC and all S6 terms lane-local.
// w-trick: S5 pre-contracts with slope coefficients; S6 is 3 row-dots.
__global__ __launch_bounds__(256, 1)
void ncde_solve(const float* __restrict__ ts, const float* __restrict__ x,
                const float* __restrict__ W0, const float* __restrict__ b0,
                const float* __restrict__ W1, const float* __restrict__ b1,
                const float* __restrict__ W2, const float* __restrict__ b2,
                const float* __restrict__ V0, const float* __restrict__ c0,
                const float* __restrict__ V1, const float* __restrict__ c1,
                const float* __restrict__ V2, const float* __restrict__ c2,
                const float* __restrict__ R, const float* __restrict__ rb,
                float* __restrict__ out)
{
    const int b = blockIdx.x;
    const int t = threadIdx.x;           // 0..255
    const int r = t >> 2, q = t & 3;     // row slot [0,64), K-slice
    const int prow = t >> 3, poct = t & 7;   // projection: 32 rows x 8 lanes

    __shared__ __align__(16) float RSh[OUTD*68];
    __shared__ __align__(16) float ySh[64];
    __shared__ __align__(16) float yp[32], y2p[32];      // 64 halves each
    __shared__ __align__(16) float a0H[64], a1H[64];     // 128 halves each
    __shared__ __align__(16) float mpH[96];              // 192 halves (d-major 3x64)
    __shared__ __align__(16) float u0H[192], wH[192];    // 3x128 halves; fp32 scratch in init
    __shared__ float slopesSh[NW][6];
    __shared__ float dtsSh[NSTEP];

    // ---- fp16-packed quad-slice weight carriers: 24 float4 = 96 VGPR ----
    float4 v0c[2][2], v1c[2][4], v2c[3][4];
    {
        auto pkld = [](const float* src)->float4{
            const float4* p=(const float4*)src;
            float4 a=p[0], c=p[1];
            float4 rr; rr.x=pack2(a.x,a.y); rr.y=pack2(a.z,a.w); rr.z=pack2(c.x,c.y); rr.w=pack2(c.z,c.w);
            return rr;
        };
        #pragma unroll
        for (int i=0;i<2;i++){
            const float* base = V0 + (r+64*i)*64 + q*16;
            v0c[i][0]=pkld(base); v0c[i][1]=pkld(base+8);
        }
        #pragma unroll
        for (int i=0;i<2;i++){
            const float* base = V1 + (r+64*i)*128 + q*32;
            #pragma unroll
            for (int k=0;k<4;k++) v1c[i][k]=pkld(base+8*k);
        }
        #pragma unroll
        for (int i=0;i<3;i++){
            const float* base = V2 + (r+64*i)*128 + q*32;
            #pragma unroll
            for (int k=0;k<4;k++) v2c[i][k]=pkld(base+8*k);
        }
        #pragma unroll
        for (int i=0;i<2;i++){ PIN4(v0c[i][0]); PIN4(v0c[i][1]); }
        #pragma unroll
        for (int i=0;i<2;i++){
            #pragma unroll
            for (int k=0;k<4;k++) PIN4(v1c[i][k]);
        }
        #pragma unroll
        for (int i=0;i<3;i++){
            #pragma unroll
            for (int k=0;k<4;k++) PIN4(v2c[i][k]);
        }
    }
    const float c0A=c0[r], c0B=c0[64+r];
    const float c1A=c1[r], c1B=c1[64+r];
    const float c2a=c2[r], c2b=c2[64+r], c2c=c2[128+r];
    const float rbp = rb[prow & 31];

    for (int i=t; i<OUTD*64; i+=256) RSh[(i>>6)*68 + (i&63)] = R[i];
    const float* tsb = ts + (size_t)b*TT;
    if (t < NSTEP) dtsSh[t] = tsb[t+1] - tsb[t];

    // ---- log-signature slopes (threads 0..15) ----
    if (t < NW) {
        const int w = t;
        const float* xs = x + (size_t)(b*TT + w*WINW)*3;
        float x0c[3] = {xs[0], xs[1], xs[2]};
        float prev[3] = {x0c[0], x0c[1], x0c[2]};
        float am01=0.f, am02=0.f, am12=0.f, am10=0.f, am20=0.f, am21=0.f;
        #pragma unroll
        for (int k=0;k<WINW;k++) {
            float cur[3] = {xs[(k+1)*3+0], xs[(k+1)*3+1], xs[(k+1)*3+2]};
            float rel[3], dv[3];
            #pragma unroll
            for (int c=0;c<3;c++){ rel[c]=prev[c]-x0c[c]; dv[c]=cur[c]-prev[c]; }
            am01 += rel[0]*dv[1]; am10 += rel[1]*dv[0];
            am02 += rel[0]*dv[2]; am20 += rel[2]*dv[0];
            am12 += rel[1]*dv[2]; am21 += rel[2]*dv[1];
            prev[0]=cur[0]; prev[1]=cur[1]; prev[2]=cur[2];
        }
        const float invden = 1.f/(tsb[(w+1)*WINW] - tsb[w*WINW]);
        slopesSh[w][0] = (prev[0]-x0c[0])*invden;
        slopesSh[w][1] = (prev[1]-x0c[1])*invden;
        slopesSh[w][2] = (prev[2]-x0c[2])*invden;
        slopesSh[w][3] = 0.5f*(am01-am10)*invden;
        slopesSh[w][4] = 0.5f*(am02-am20)*invden;
        slopesSh[w][5] = 0.5f*(am12-am21)*invden;
    }

    // ---- h0 = init_mlp(x[b,0,:]) fp32 (u0H/wH as scratch) ----
    if (t < 128) {
        const float xv0 = x[(size_t)b*TT*3+0];
        const float xv1 = x[(size_t)b*TT*3+1];
        const float xv2 = x[(size_t)b*TT*3+2];
        float acc = b0[t] + W0[t*3]*xv0 + W0[t*3+1]*xv1 + W0[t*3+2]*xv2;
        float sp, sg; sigsp(acc, sp, sg);
        u0H[t] = sp;
    }
    __syncthreads();
    if (t < 128) {
        float acc = b1[t];
        const float4* rw = (const float4*)(W1 + t*128);
        #pragma unroll 8
        for (int k=0;k<32;k++){ float4 wv=rw[k]; float4 av=*(const float4*)&u0H[4*k]; DOT4(acc,wv,av); }
        float sp, sg; sigsp(acc, sp, sg);
        wH[t] = sp;
    }
    __syncthreads();
    if (t < 64) {
        float acc = b2[t];
        const float4* rw = (const float4*)(W2 + t*128);
        #pragma unroll 8
        for (int k=0;k<32;k++){ float4 wv=rw[k]; float4 av=*(const float4*)&wH[4*k]; DOT4(acc,wv,av); }
        ySh[t] = acc;
        ((_Float16*)yp)[t] = (_Float16)acc;
    }
    __syncthreads();

    float yreg = ySh[r];    // lane-local state (quad-redundant)
    float k1r = 0.f;
    float S0,S1,S2,S3,S4,S5;

    auto Feval = [&](const float* ypIn, bool first, float dtc) {
        float sig0A,sig0B,sig1A,sig1B,mA,mB,mC,dtA,dtB,dtC;
        // S1: z0 = V0@y + c0 (rows r, 64+r)
        {
            const float4* Y = (const float4*)ypIn;
            float4 y0=Y[q*2], y1=Y[q*2+1];
            float zA = dot2q(v0c[0][0],y0,0.f); zA = dot2q(v0c[0][1],y1,zA);
            float zB = dot2q(v0c[1][0],y0,0.f); zB = dot2q(v0c[1][1],y1,zB);
            RED4(zA); RED4(zB);
            zA += c0A; zB += c0B;
            float spA, spB;
            sigsp(zA, spA, sig0A); sigsp(zB, spB, sig0B);
            if (!q){
                ((_Float16*)a0H)[r]    = (_Float16)spA;
                ((_Float16*)a0H)[64+r] = (_Float16)spB;
            }
        }
        __syncthreads();
        // S2: z1 = V1@a0 + c1 (rows r, 64+r) — split chains
        {
            const float4* A = (const float4*)a0H + q*4;
            float4 a0=A[0],a1=A[1],a2=A[2],a3=A[3];
            float zAa=dot2q(v1c[0][0],a0,0.f); zAa=dot2q(v1c[0][1],a1,zAa);
            float zAb=dot2q(v1c[0][2],a2,0.f); zAb=dot2q(v1c[0][3],a3,zAb);
            float zBa=dot2q(v1c[1][0],a0,0.f); zBa=dot2q(v1c[1][1],a1,zBa);
            float zBb=dot2q(v1c[1][2],a2,0.f); zBb=dot2q(v1c[1][3],a3,zBb);
            float zA=zAa+zAb, zB=zBa+zBb;
            RED4(zA); RED4(zB);
            zA += c1A; zB += c1B;
            float spA, spB;
            sigsp(zA, spA, sig1A); sigsp(zB, spB, sig1B);
            if (!q){
                ((_Float16*)a1H)[r]    = (_Float16)spA;
                ((_Float16*)a1H)[64+r] = (_Float16)spB;
            }
        }
        __syncthreads();
        // S3: m = tanh(V2@a1 + c2) (rows r, 64+r, 128+r — ALL lane-local)
        {
            const float4* A = (const float4*)a1H + q*4;
            float4 a0=A[0],a1=A[1],a2=A[2],a3=A[3];
            float zAa=dot2q(v2c[0][0],a0,0.f); zAa=dot2q(v2c[0][1],a1,zAa);
            float zAb=dot2q(v2c[0][2],a2,0.f); zAb=dot2q(v2c[0][3],a3,zAb);
            float zBa=dot2q(v2c[1][0],a0,0.f); zBa=dot2q(v2c[1][1],a1,zBa);
            float zBb=dot2q(v2c[1][2],a2,0.f); zBb=dot2q(v2c[1][3],a3,zBb);
            float zCa=dot2q(v2c[2][0],a0,0.f); zCa=dot2q(v2c[2][1],a1,zCa);
            float zCb=dot2q(v2c[2][2],a2,0.f); zCb=dot2q(v2c[2][3],a3,zCb);
            float zA=zAa+zAb, zB=zBa+zBb, zC=zCa+zCb;
            RED4(zA); RED4(zB); RED4(zC);
            mA=tanh_f(zA+c2a); mB=tanh_f(zB+c2b); mC=tanh_f(zC+c2c);
            dtA=1.f-mA*mA; dtB=1.f-mB*mB; dtC=1.f-mC*mC;
            if (!q){
                ((_Float16*)mpH)[r]     = (_Float16)mA;
                ((_Float16*)mpH)[64+r]  = (_Float16)mB;
                ((_Float16*)mpH)[128+r] = (_Float16)mC;
            }
        }
        __syncthreads();
        // S4: u0[d] = sig0 ⊙ (V0 @ m[d]) (rows r, 64+r × 3 tangents)
        {
            const float4* M = (const float4*)mpH;
            float4 g0a=M[q*2],    g0b=M[q*2+1];
            float4 g1a=M[8+q*2],  g1b=M[8+q*2+1];
            float4 g2a=M[16+q*2], g2b=M[16+q*2+1];
            float t0A=dot2q(v0c[0][0],g0a,0.f); t0A=dot2q(v0c[0][1],g0b,t0A);
            float t1A=dot2q(v0c[0][0],g1a,0.f); t1A=dot2q(v0c[0][1],g1b,t1A);
            float t2A=dot2q(v0c[0][0],g2a,0.f); t2A=dot2q(v0c[0][1],g2b,t2A);
            float t0B=dot2q(v0c[1][0],g0a,0.f); t0B=dot2q(v0c[1][1],g0b,t0B);
            float t1B=dot2q(v0c[1][0],g1a,0.f); t1B=dot2q(v0c[1][1],g1b,t1B);
            float t2B=dot2q(v0c[1][0],g2a,0.f); t2B=dot2q(v0c[1][1],g2b,t2B);
            RED4(t0A); RED4(t1A); RED4(t2A);
            RED4(t0B); RED4(t1B); RED4(t2B);
            if (!q){
                ((_Float16*)u0H)[r]      = (_Float16)(sig0A*t0A);
                ((_Float16*)u0H)[64+r]   = (_Float16)(sig0B*t0B);
                ((_Float16*)u0H)[128+r]  = (_Float16)(sig0A*t1A);
                ((_Float16*)u0H)[192+r]  = (_Float16)(sig0B*t1B);
                ((_Float16*)u0H)[256+r]  = (_Float16)(sig0A*t2A);
                ((_Float16*)u0H)[320+r]  = (_Float16)(sig0B*t2B);
            }
        }
        __syncthreads();
        // S5: t[d] = V1@u0[d]; pre-contract into w0,w1,w2 per row (lane-local FMAs):
        //   w0 = sig1*(S3*t1 + S4*t2); w1 = sig1*(S3*t0 - S5*t2); w2 = sig1*(S4*t0 + S5*t1)
        {
            const float4* U = (const float4*)u0H;
            float t0Aa=0.f,t0Ab=0.f,t1Aa=0.f,t1Ab=0.f,t2Aa=0.f,t2Ab=0.f;
            float t0Ba=0.f,t0Bb=0.f,t1Ba=0.f,t1Bb=0.f,t2Ba=0.f,t2Bb=0.f;
            #pragma unroll
            for (int k=0;k<2;k++){
                float4 wa=v1c[0][k], wb=v1c[1][k];
                float4 g0=U[q*4+k], g1=U[16+q*4+k], g2=U[32+q*4+k];
                t0Aa=dot2q(wa,g0,t0Aa); t1Aa=dot2q(wa,g1,t1Aa); t2Aa=dot2q(wa,g2,t2Aa);
                t0Ba=dot2q(wb,g0,t0Ba); t1Ba=dot2q(wb,g1,t1Ba); t2Ba=dot2q(wb,g2,t2Ba);
            }
            #pragma unroll
            for (int k=2;k<4;k++){
                float4 wa=v1c[0][k], wb=v1c[1][k];
                float4 g0=U[q*4+k], g1=U[16+q*4+k], g2=U[32+q*4+k];
                t0Ab=dot2q(wa,g0,t0Ab); t1Ab=dot2q(wa,g1,t1Ab); t2Ab=dot2q(wa,g2,t2Ab);
                t0Bb=dot2q(wb,g0,t0Bb); t1Bb=dot2q(wb,g1,t1Bb); t2Bb=dot2q(wb,g2,t2Bb);
            }
            float t0A=t0Aa+t0Ab, t1A=t1Aa+t1Ab, t2A=t2Aa+t2Ab;
            float t0B=t0Ba+t0Bb, t1B=t1Ba+t1Bb, t2B=t2Ba+t2Bb;
            RED4(t0A); RED4(t1A); RED4(t2A);
            RED4(t0B); RED4(t1B); RED4(t2B);
            if (!q){
                ((_Float16*)wH)[r]      = (_Float16)(sig1A*(S3*t1A + S4*t2A));
                ((_Float16*)wH)[64+r]   = (_Float16)(sig1B*(S3*t1B + S4*t2B));
                ((_Float16*)wH)[128+r]  = (_Float16)(sig1A*(S3*t0A - S5*t2A));
                ((_Float16*)wH)[192+r]  = (_Float16)(sig1B*(S3*t0B - S5*t2B));
                ((_Float16*)wH)[256+r]  = (_Float16)(sig1A*(S4*t0A + S5*t1A));
                ((_Float16*)wH)[320+r]  = (_Float16)(sig1B*(S4*t0B + S5*t1B));
            }
        }
        __syncthreads();
        // S6+S7 fused: D_b = V2[r+64b] @ w_b (3 dots, w-trick); all terms lane-local.
        {
            const float4* W = (const float4*)wH;
            float D0a=dot2q(v2c[0][0],W[q*4+0],0.f);   D0a=dot2q(v2c[0][1],W[q*4+1],D0a);
            float D0b=dot2q(v2c[0][2],W[q*4+2],0.f);   D0b=dot2q(v2c[0][3],W[q*4+3],D0b);
            float D1a=dot2q(v2c[1][0],W[16+q*4+0],0.f);D1a=dot2q(v2c[1][1],W[16+q*4+1],D1a);
            float D1b=dot2q(v2c[1][2],W[16+q*4+2],0.f);D1b=dot2q(v2c[1][3],W[16+q*4+3],D1b);
            float D2a=dot2q(v2c[2][0],W[32+q*4+0],0.f);D2a=dot2q(v2c[2][1],W[32+q*4+1],D2a);
            float D2b=dot2q(v2c[2][2],W[32+q*4+2],0.f);D2b=dot2q(v2c[2][3],W[32+q*4+3],D2b);
            float D0=D0a+D0b, D1=D1a+D1b, D2=D2a+D2b;
            RED4(D0); RED4(D1); RED4(D2);
            float kk = mA*S0 + mB*S1 + mC*S2 - dtA*D0 + dtB*D1 + dtC*D2;
            if (first){
                k1r = kk;
                float y2 = yreg + dtc*kk;
                if (!q) ((_Float16*)y2p)[r] = (_Float16)y2;
            } else {
                yreg += 0.5f*dtc*(k1r + kk);
                if (!q){ ((_Float16*)yp)[r] = (_Float16)yreg; ySh[r] = yreg; }
            }
        }
        __syncthreads();
    };

    // ---- projection (all 256 threads, overlapped into S1's interval) ----
    auto proj = [&](int stp) {
        const float4* rr = (const float4*)(RSh + prow*68 + poct*8);
        const float4* yy = (const float4*)(ySh + poct*8);
        float pacc = 0.f;
        DOT4(pacc, rr[0], yy[0]); DOT4(pacc, rr[1], yy[1]);
        pacc += dpp_xor1(pacc);
        pacc += dpp_xor2(pacc);
        pacc += dpp_hmir(pacc);
        if (!poct) out[(size_t)(b*TT + stp)*OUTD + prow] = tanh_f(pacc + rbp);
    };

    // ---- Heun scan ----
    for (int step=0; step<NSTEP; ++step) {
        proj(step);
        const int w = step >> 3;
        S0=slopesSh[w][0]; S1=slopesSh[w][1]; S2=slopesSh[w][2];
        S3=slopesSh[w][3]; S4=slopesSh[w][4]; S5=slopesSh[w][5];
        const float dtc = dtsSh[step];
        Feval(yp,  true,  dtc);
        Feval(y2p, false, dtc);
    }
    proj(NSTEP);
}

extern "C" void kernel_launch(void* const* d_in, const int* in_sizes, int n_in,
                              void* d_out, int out_size, void* d_ws, size_t ws_size,
                              hipStream_t stream) {
    const float* ts = (const float*)d_in[0];
    const float* x  = (const float*)d_in[1];
    const float* W0 = (const float*)d_in[2];
    const float* b0 = (const float*)d_in[3];
    const float* W1 = (const float*)d_in[4];
    const float* b1 = (const float*)d_in[5];
    const float* W2 = (const float*)d_in[6];
    const float* b2 = (const float*)d_in[7];
    const float* V0 = (const float*)d_in[8];
    const float* c0 = (const float*)d_in[9];
    const float* V1 = (const float*)d_in[10];
    const float* c1 = (const float*)d_in[11];
    const float* V2 = (const float*)d_in[12];
    const float* c2 = (const float*)d_in[13];
    const float* R  = (const float*)d_in[14];
    const float* rb = (const float*)d_in[15];
    float* out = (float*)d_out;

    ncde_solve<<<dim3(BB), dim3(256), 0, stream>>>(
        ts, x, W0, b0, W1, b1, W2, b2, V0, c0, V1, c1, V2, c2, R, rb, out);
}